// Round 6
// baseline (557.009 us; speedup 1.0000x reference)
//
#include <hip/hip_runtime.h>
#include <hip/hip_bf16.h>

typedef __hip_bfloat16 bf16;
typedef __attribute__((ext_vector_type(8))) short short8;
typedef __attribute__((ext_vector_type(8))) unsigned short ushort8v;
typedef __attribute__((ext_vector_type(4))) float float4v;

#define NN 20000
#define EE 160000
#define ET (NN + EE)

__device__ __forceinline__ float bf2f(bf16 v){ return __bfloat162float(v); }
__device__ __forceinline__ float raw2f(unsigned short u){ return __uint_as_float(((unsigned)u) << 16); }
__device__ __forceinline__ unsigned short f2raw(float f){
  bf16 h = __float2bfloat16(f);
  return *(unsigned short*)&h;
}

// ---------------- inline dtype detection (per-wave ballot; all waves agree) ----------------
__device__ __forceinline__ int detect_f32(const void* raw, int nwords, int lane){
  unsigned v = ((const unsigned*)raw)[lane % nwords];
  int e8 = (v >> 7) & 0xFF;
  int looks = (e8 >= 100 && e8 <= 140) ? 1 : 0;
  unsigned long long mz = __ballot(v == 0u);
  unsigned long long ml = __ballot(looks);
  int nz = __popcll(mz);
  int nonz = 64 - nz;
  int nl = __popcll(ml);
  return (nonz > 0 && 2*nl >= nonz) ? 0 : 1;
}

__device__ __forceinline__ int detect_i64(const int* eiraw, int lane){
  int odd = eiraw[2*lane + 1];
  unsigned long long m2 = __ballot(odd != 0);
  return (m2 == 0ULL) ? 1 : 0;
}

// ---------------- fused preprocessing kernel ----------------
struct P13 { const void* src[13]; int off[13]; int n[13]; };
struct PrepArgs {
  const void* xraw; bf16* Xc;
  const void* w1raw; bf16* Wt1;
  const void* w2raw; bf16* Wt2;
  const void* w3raw; bf16* Wt3;
  const int* eiraw; int* eic;
  P13 p13; float* prm;
  int* counts;
  float* esA; float* edA;
};

__device__ __forceinline__ void do_transpose(float (*tile)[33], const void* raw,
    bf16* wt, int K, int M, int f, int bx, int by, int t){
  int kb = by*32, mb = bx*32;
  int tx = t & 31, ty = t >> 5;   // 32 x 8
  for (int r = 0; r < 4; r++){
    int k = kb + ty + r*8;
    int m = mb + tx;
    float v = f ? ((const float*)raw)[(size_t)k*M+m] : bf2f(((const bf16*)raw)[(size_t)k*M+m]);
    tile[ty + r*8][tx] = v;
  }
  __syncthreads();
  for (int r = 0; r < 4; r++){
    int m = mb + ty + r*8;
    int k = kb + tx;
    wt[(size_t)m*K + k] = __float2bfloat16(tile[tx][ty + r*8]);
  }
}

__global__ __launch_bounds__(256) void k_prep(PrepArgs A){
  __shared__ float tile[32][33];
  int b = blockIdx.x, t = threadIdx.x;
  int lane = t & 63;
  if (b < 10000){                                 // cvt X -> bf16
    int f = detect_f32(A.xraw, NN*128/2, lane);
    int i = b*256 + t;
    if (f) A.Xc[i] = __float2bfloat16(((const float*)A.xraw)[i]);
    else   A.Xc[i] = ((const bf16*)A.xraw)[i];
  } else if (b < 10128){                          // transpose W1 [128][1024] -> [1024][128]
    int f = detect_f32(A.w1raw, 128*1024/2, lane);
    int r = b - 10000;
    do_transpose(tile, A.w1raw, A.Wt1, 128, 1024, f, r & 31, r >> 5, t);
  } else if (b < 11152){                          // transpose W2 [1024][1024]
    int f = detect_f32(A.w2raw, 1024*1024/2, lane);
    int r = b - 10128;
    do_transpose(tile, A.w2raw, A.Wt2, 1024, 1024, f, r & 31, r >> 5, t);
  } else if (b < 11664){                          // transpose W3 [1024][512] -> [512][1024]
    int f = detect_f32(A.w3raw, 1024*512/2, lane);
    int r = b - 11152;
    do_transpose(tile, A.w3raw, A.Wt3, 1024, 512, f, r & 15, r >> 4, t);
  } else if (b < 12914){                          // cvte
    int f64 = detect_i64(A.eiraw, lane);
    int i = (b - 11664)*256 + t;
    if (i < 2*EE) A.eic[i] = f64 ? A.eiraw[2*i] : A.eiraw[i];
  } else if (b < 12927){                          // params -> fp32
    int pb = b - 12914;
    const void* s = A.p13.src[pb];
    int n = A.p13.n[pb];
    int f = detect_f32(s, n/2, lane);
    float* d = A.prm + A.p13.off[pb];
    for (int i = t; i < n; i += 256)
      d[i] = f ? ((const float*)s)[i] : bf2f(((const bf16*)s)[i]);
  } else if (b < 13006){                          // init_counts
    int i = (b - 12927)*256 + t;
    if (i < NN) A.counts[i] = 1;
  } else {                                        // zero esA/edA (NN*4 floats each)
    int i = (b - 13006)*256 + t;
    if (i < NN*4){ A.esA[i] = 0.f; A.edA[i] = 0.f; }
  }
}

// ---------------- CSR build ----------------
__global__ void k_hist(const int* __restrict__ ei, int* __restrict__ counts){
  int e = blockIdx.x*256 + threadIdx.x;
  if (e < EE){
    int d = ei[EE + e];
    if (d >= 0 && d < NN) atomicAdd(&counts[d], 1);
  }
}

// scan + self-loop insertion fused; counts/rp/cursor/col are DISTINCT buffers (no aliasing)
__global__ __launch_bounds__(1024) void k_scan(const int* __restrict__ counts, int* __restrict__ rp,
    int* __restrict__ cursor, int* __restrict__ col){
  __shared__ int wsum[16];
  __shared__ int sc;
  int t = threadIdx.x, lane = t & 63, wv = t >> 6;
  if (t == 0) sc = 0;
  __syncthreads();
  for (int base = 0; base < NN; base += 1024){
    int i = base + t;
    int v = (i < NN) ? counts[i] : 0;
    int x = v;
    #pragma unroll
    for (int o = 1; o < 64; o <<= 1){
      int y = __shfl_up(x, o, 64);
      if (lane >= o) x += y;
    }
    if (lane == 63) wsum[wv] = x;
    __syncthreads();
    if (wv == 0 && lane < 16){
      int w = wsum[lane];
      #pragma unroll
      for (int o = 1; o < 16; o <<= 1){
        int y = __shfl_up(w, o, 16);
        if ((lane & 15) >= o) w += y;
      }
      wsum[lane] = w;
    }
    __syncthreads();
    int carry = sc;
    int wpre = (wv > 0) ? wsum[wv-1] : 0;
    if (i < NN){
      int p = carry + wpre + x - v;   // exclusive
      rp[i] = p;
      col[p] = i;                     // self loop at segment head
      cursor[i] = p + 1;
    }
    __syncthreads();
    if (t == 1023) sc = carry + wsum[15];
    __syncthreads();
  }
  if (t == 0) rp[NN] = sc;
}

__global__ void k_scatter(const int* __restrict__ ei, int* __restrict__ cursor, int* __restrict__ col){
  int e = blockIdx.x*256 + threadIdx.x;
  if (e < EE){
    int s = ei[e], d = ei[EE + e];
    if (d >= 0 && d < NN){
      int pos = atomicAdd(&cursor[d], 1);
      col[pos] = s;
    }
  }
}

// ---------------- MFMA GEMM (layer 1 only): 64x128 tile, BK=64 single-buffer ----------------
// ROUND-0 STRUCTURE (proven ~77-80us for K=1024; here only used at K=128 where it is ~12us).
__global__ __launch_bounds__(256) void k_gemm_mfma(
    const bf16* __restrict__ X, const bf16* __restrict__ Wt, bf16* __restrict__ Y,
    const float* __restrict__ as_, const float* __restrict__ ad_,
    float* __restrict__ es, float* __restrict__ ed,
    int K, int M, int C, int H)
{
  __shared__ bf16 Xs[64*64];    // 8 KB
  __shared__ bf16 Bs[128*64];   // 16 KB
  int ncols = gridDim.x;
  int bid = blockIdx.y * ncols + blockIdx.x;
  int xcd  = bid & 7;
  int rest = bid >> 3;
  int colb = rest % ncols;
  int rowb = xcd + 8 * (rest / ncols);
  int r0 = rowb * 64;
  if (r0 >= NN) return;
  int c0 = colb * 128;

  int tid  = threadIdx.x;
  int wave = tid >> 6, lane = tid & 63;
  int quad = lane >> 4, l15 = lane & 15;
  int wr = (wave >> 1) * 32;     // 2 row-groups of 32
  int wc = (wave & 1) * 64;      // 2 col-groups of 64
  int sw = l15 & 7;

  float4v acc[2][4];
  #pragma unroll
  for (int i=0;i<2;i++)
    #pragma unroll
    for (int j=0;j<4;j++)
      acc[i][j] = (float4v){0.f,0.f,0.f,0.f};

  for (int k0 = 0; k0 < K; k0 += 64){
    #pragma unroll
    for (int i = 0; i < 2; i++){            // Xs: 512 chunks of 16B
      int ch = i*256 + tid;
      int row = ch >> 3, kl = ch & 7;
      int kg = kl ^ (row & 7);
      const bf16* gx = X + (size_t)(r0 + row)*K + k0 + kg*8;
      __builtin_amdgcn_global_load_lds(
        (const __attribute__((address_space(1))) unsigned int*)gx,
        (__attribute__((address_space(3))) unsigned int*)(Xs + ch*8), 16, 0, 0);
    }
    #pragma unroll
    for (int i = 0; i < 4; i++){            // Bs: 1024 chunks of 16B
      int ch = i*256 + tid;
      int row = ch >> 3, kl = ch & 7;
      int kg = kl ^ (row & 7);
      const bf16* gb = Wt + (size_t)(c0 + row)*K + k0 + kg*8;
      __builtin_amdgcn_global_load_lds(
        (const __attribute__((address_space(1))) unsigned int*)gb,
        (__attribute__((address_space(3))) unsigned int*)(Bs + ch*8), 16, 0, 0);
    }
    __syncthreads();

    #pragma unroll
    for (int kk = 0; kk < 2; kk++){         // two 32-wide K slices, in order (bit-identical accum)
      int kp = quad + kk*4;
      short8 af[2], bfr[4];
      #pragma unroll
      for (int i = 0; i < 2; i++){
        int r = wr + i*16 + l15;
        af[i] = *(const short8*)(Xs + ((size_t)r*8 + (kp ^ sw))*8);
      }
      #pragma unroll
      for (int j = 0; j < 4; j++){
        int r = wc + j*16 + l15;
        bfr[j] = *(const short8*)(Bs + ((size_t)r*8 + (kp ^ sw))*8);
      }
      #pragma unroll
      for (int i = 0; i < 2; i++)
        #pragma unroll
        for (int j = 0; j < 4; j++)
          acc[i][j] = __builtin_amdgcn_mfma_f32_16x16x32_bf16(af[i], bfr[j], acc[i][j], 0, 0, 0);
    }
    __syncthreads();
  }

  int h = c0 / C;
  float asv[4], adv[4];
  #pragma unroll
  for (int j = 0; j < 4; j++){
    int colj = c0 + wc + j*16 + l15;
    asv[j] = as_[colj]; adv[j] = ad_[colj];
  }
  #pragma unroll
  for (int i = 0; i < 2; i++){
    int rbase = r0 + wr + i*16 + quad*4;
    #pragma unroll
    for (int rg = 0; rg < 4; rg++){
      int row = rbase + rg;
      bool ok = (row < NN);
      float pe = 0.f, pd = 0.f;
      #pragma unroll
      for (int j = 0; j < 4; j++){
        float v = acc[i][j][rg];
        int colj = c0 + wc + j*16 + l15;
        if (ok) Y[(size_t)row*M + colj] = __float2bfloat16(v);
        pe += v * asv[j];
        pd += v * adv[j];
      }
      #pragma unroll
      for (int o = 1; o < 16; o <<= 1){
        pe += __shfl_xor(pe, o, 64);
        pd += __shfl_xor(pd, o, 64);
      }
      if (ok && l15 == 0){
        atomicAdd(&es[row*H + h], pe);
        atomicAdd(&ed[row*H + h], pd);
      }
    }
  }
}

// ---------------- 8-phase 256x256 MFMA GEMM (layers 2,3; K multiple of 128) ----------------
// Port of the verified 8-phase template (T2+T3+T4+T5): BM=BN=256, BK=64, 8 waves (2Mx4N),
// wave tile 128x64, acc[8][4], LDS 128KB dbuf. Same XOR-chunk swizzle + fragment formulas as
// the proven 64x128 kernel (0 bank conflicts), so per-element K-accum order is IDENTICAL ->
// bit-identical output (absmax canary).
// Phase plan per iteration (2 K-tiles: buf0=t0, buf1=t0+1), reads/stages chosen so every
// stage lands in a window where its target region's reads have retired (via the per-phase
// double barrier + lgkmcnt(0) before MFMA):
//   P1: read buf0{A0,B0,B1}; stage buf1.Bh0(t0+1); MFMA Q00   (buf1.B last read prev-P5)
//   P2: read buf0{A1};       stage buf1.Bh1(t0+1); MFMA Q01
//   P3:                      stage buf0.Ah0(t0+2); MFMA Q11   (buf0.A reads ended P2)
//   P4:                      stage buf0.Ah1(t0+2); MFMA Q10; vmcnt(4)  <- buf1 complete
//   P5: read buf1{A0,B0,B1}; stage buf0.Bh0(t0+2); MFMA Q00   (buf0.B reads ended P1)
//   P6: read buf1{A1};       stage buf0.Bh1(t0+2); MFMA Q01
//   P7:                      stage buf1.Ah0(t0+3); MFMA Q11   (buf1.A reads ended P6)
//   P8:                      stage buf1.Ah1(t0+3); MFMA Q10; vmcnt(4)  <- buf0 complete
// Ledger: 2 loads/half-stage, 12 max outstanding; vmcnt(4) at P4 leaves only P3,P4's stages
// in flight => P1,P2 (buf1 tile) landed; at P8 leaves P7,P8 => P3..P6 (buf0 tile) landed.
// Never drains to 0 except the peeled final iteration. Extra compiler loads only make the
// counted waits MORE conservative (oldest-first retire) -> safe.
__global__ __launch_bounds__(512, 2) void k_gemm_8p(
    const bf16* __restrict__ X, const bf16* __restrict__ Wt, bf16* __restrict__ Y,
    const float* __restrict__ as_, const float* __restrict__ ad_,
    float* __restrict__ es, float* __restrict__ ed,
    int K, int M, int C, int H)
{
  __shared__ bf16 As[2][16384];   // 2 x 32KB
  __shared__ bf16 Bs[2][16384];   // 2 x 32KB -> 128KB total
  int ncols = gridDim.x;
  int bid = blockIdx.y * ncols + blockIdx.x;
  int xcd  = bid & 7;
  int rest = bid >> 3;
  int colb = rest % ncols;
  int rowb = xcd + 8 * (rest / ncols);
  int r0 = rowb * 256;
  if (r0 >= NN) return;
  int c0 = colb * 256;

  int tid  = threadIdx.x;
  int wave = tid >> 6, lane = tid & 63;
  int wm = wave >> 2, wn = wave & 3;     // 2 x 4 wave grid
  int quad = lane >> 4, l15 = lane & 15;
  int sw = l15 & 7;
  int ar = wm * 128;                      // wave A-row base (local)
  int bc = wn * 64;                       // wave B-col base (local)

  float4v acc[8][4];
  #pragma unroll
  for (int i=0;i<8;i++)
    #pragma unroll
    for (int j=0;j<4;j++) acc[i][j] = (float4v){0.f,0.f,0.f,0.f};

  int nst   = K >> 6;    // 16
  int niter = nst >> 1;  // 8

  // half-tile stage: 128 rows x 64 K = 1024 chunks of 16B; 512 threads x 2 chunks.
  // LDS dest linear in chunk (gload_lds is wave-uniform-base+lane*16); swizzle via GLOBAL kg.
#define SA8(b, hh, kt) { _Pragma("unroll") for (int i_=0;i_<2;i_++){ \
    int ch = i_*512 + tid; int row = (hh)*128 + (ch>>3); int kg = (ch&7) ^ (row&7); \
    const bf16* g = X + (size_t)(r0+row)*K + (kt)*64 + kg*8; \
    __builtin_amdgcn_global_load_lds((const __attribute__((address_space(1))) unsigned int*)g, \
      (__attribute__((address_space(3))) unsigned int*)(&As[b][((hh)*1024 + ch)*8]), 16, 0, 0); } }
#define SB8(b, hh, kt) { _Pragma("unroll") for (int i_=0;i_<2;i_++){ \
    int ch = i_*512 + tid; int row = (hh)*128 + (ch>>3); int kg = (ch&7) ^ (row&7); \
    const bf16* g = Wt + (size_t)(c0+row)*K + (kt)*64 + kg*8; \
    __builtin_amdgcn_global_load_lds((const __attribute__((address_space(1))) unsigned int*)g, \
      (__attribute__((address_space(3))) unsigned int*)(&Bs[b][((hh)*1024 + ch)*8]), 16, 0, 0); } }

#define PBAR() { __builtin_amdgcn_sched_barrier(0); __builtin_amdgcn_s_barrier(); __builtin_amdgcn_sched_barrier(0); }
#define LGKM0() { asm volatile("s_waitcnt lgkmcnt(0)" ::: "memory"); __builtin_amdgcn_sched_barrier(0); }

  short8 a0[2][4], a1[2][4], b0[2][2], b1[2][2];

#define LDA0(b) { _Pragma("unroll") for (int kk=0;kk<2;kk++){ int kp = quad + kk*4; \
    _Pragma("unroll") for (int i=0;i<4;i++){ int r = ar + i*16 + l15; \
      a0[kk][i] = *(const short8*)(&As[b][((r*8) + (kp^sw))*8]); } } }
#define LDA1(b) { _Pragma("unroll") for (int kk=0;kk<2;kk++){ int kp = quad + kk*4; \
    _Pragma("unroll") for (int i=0;i<4;i++){ int r = ar + 64 + i*16 + l15; \
      a1[kk][i] = *(const short8*)(&As[b][((r*8) + (kp^sw))*8]); } } }
#define LDB0(b) { _Pragma("unroll") for (int kk=0;kk<2;kk++){ int kp = quad + kk*4; \
    _Pragma("unroll") for (int j=0;j<2;j++){ int r = bc + j*16 + l15; \
      b0[kk][j] = *(const short8*)(&Bs[b][((r*8) + (kp^sw))*8]); } } }
#define LDB1(b) { _Pragma("unroll") for (int kk=0;kk<2;kk++){ int kp = quad + kk*4; \
    _Pragma("unroll") for (int j=0;j<2;j++){ int r = bc + 32 + j*16 + l15; \
      b1[kk][j] = *(const short8*)(&Bs[b][((r*8) + (kp^sw))*8]); } } }

  // per-element K-order: kk ascending within tile, tiles ascending -> bit-identical to old.
#define MQ(AR, BR, I0, J0) { __builtin_amdgcn_s_setprio(1); \
    _Pragma("unroll") for (int kk=0;kk<2;kk++) \
    _Pragma("unroll") for (int i=0;i<4;i++) \
    _Pragma("unroll") for (int j=0;j<2;j++) \
      acc[(I0)+i][(J0)+j] = __builtin_amdgcn_mfma_f32_16x16x32_bf16(AR[kk][i], BR[kk][j], acc[(I0)+i][(J0)+j], 0, 0, 0); \
    __builtin_amdgcn_s_setprio(0); }

  // prologue: buf0 = tile0 (4 halves), buf1 = tile1 A-halves -> 12 loads; vmcnt(4) => buf0 landed
  SA8(0,0,0); SA8(0,1,0); SB8(0,0,0); SB8(0,1,0);
  SA8(1,0,1); SA8(1,1,1);
  asm volatile("s_waitcnt vmcnt(4)" ::: "memory");
  PBAR();

  for (int it = 0; it < niter; it++){
    int t0 = it << 1;
    bool last = (it == niter-1);
    // ---- P1 ----
    LDA0(0); LDB0(0); LDB1(0);
    SB8(1,0,t0+1);
    PBAR(); LGKM0();
    MQ(a0,b0,0,0);
    PBAR();
    // ---- P2 ----
    LDA1(0);
    SB8(1,1,t0+1);
    PBAR(); LGKM0();
    MQ(a0,b1,0,2);
    PBAR();
    // ---- P3 ----
    if (!last) SA8(0,0,t0+2);
    PBAR(); LGKM0();
    MQ(a1,b1,4,2);
    PBAR();
    // ---- P4 ----
    if (!last) SA8(0,1,t0+2);
    PBAR(); LGKM0();
    MQ(a1,b0,4,0);
    if (last){ asm volatile("s_waitcnt vmcnt(0)" ::: "memory"); }
    else     { asm volatile("s_waitcnt vmcnt(4)" ::: "memory"); }
    PBAR();
    // ---- P5 ----
    LDA0(1); LDB0(1); LDB1(1);
    if (!last) SB8(0,0,t0+2);
    PBAR(); LGKM0();
    MQ(a0,b0,0,0);
    PBAR();
    // ---- P6 ----
    LDA1(1);
    if (!last) SB8(0,1,t0+2);
    PBAR(); LGKM0();
    MQ(a0,b1,0,2);
    PBAR();
    // ---- P7 ----
    if (!last) SA8(1,0,t0+3);
    PBAR(); LGKM0();
    MQ(a1,b1,4,2);
    PBAR();
    // ---- P8 ----
    if (!last) SA8(1,1,t0+3);
    PBAR(); LGKM0();
    MQ(a1,b0,4,0);
    if (!last){ asm volatile("s_waitcnt vmcnt(4)" ::: "memory"); }
    PBAR();
  }
#undef SA8
#undef SB8
#undef PBAR
#undef LGKM0
#undef LDA0
#undef LDA1
#undef LDB0
#undef LDB1
#undef MQ

  // ---- epilogue: C write + fused es/ed (same formulas as proven kernel) ----
  int h = c0 / C;
  float asv[4], adv[4];
  #pragma unroll
  for (int j = 0; j < 4; j++){
    int colj = c0 + bc + j*16 + l15;
    asv[j] = as_[colj]; adv[j] = ad_[colj];
  }
  #pragma unroll
  for (int i = 0; i < 8; i++){
    int rbase = r0 + ar + i*16 + quad*4;
    #pragma unroll
    for (int rg = 0; rg < 4; rg++){
      int row = rbase + rg;
      bool ok = (row < NN);
      float pe = 0.f, pd = 0.f;
      #pragma unroll
      for (int j = 0; j < 4; j++){
        float v = acc[i][j][rg];
        int colj = c0 + bc + j*16 + l15;
        if (ok) Y[(size_t)row*M + colj] = __float2bfloat16(v);
        pe += v * asv[j];
        pd += v * adv[j];
      }
      #pragma unroll
      for (int o = 1; o < 16; o <<= 1){
        pe += __shfl_xor(pe, o, 64);
        pd += __shfl_xor(pd, o, 64);
      }
      if (ok && l15 == 0){
        atomicAdd(&es[row*H + h], pe);
        atomicAdd(&ed[row*H + h], pd);
      }
    }
  }
}

// ---------------- wave-per-node softmax+aggregate+bias+LN+ELU (layers 1,2; H=4) ----------------
__global__ __launch_bounds__(128) void k_aggln(const int* __restrict__ rp, const int* __restrict__ col,
    const bf16* __restrict__ xw, const float* __restrict__ es, const float* __restrict__ ed,
    const float* __restrict__ bias, const float* __restrict__ gam, const float* __restrict__ bet,
    bf16* __restrict__ act, float* __restrict__ esz, float* __restrict__ edz, int zn){
  int wv = threadIdx.x >> 6, lane = threadIdx.x & 63;
  int n = blockIdx.x*2 + wv;              // NN % 2 == 0
  int h = lane >> 4;
  int cb = lane * 16;
  int e0 = rp[n], e1 = rp[n+1], deg = e1 - e0;
  float4 ed4 = *(const float4*)&ed[n*4];
  const unsigned short* xwu = (const unsigned short*)xw;

  float acc[16];
  #pragma unroll
  for (int c=0;c<16;c++) acc[c]=0.f;

  if (deg <= 64){
    int src = 0;
    float l0=-1e30f, l1=-1e30f, l2=-1e30f, l3=-1e30f;
    if (lane < deg){
      src = col[e0 + lane];
      float4 e4 = *(const float4*)&es[src*4];
      float v;
      v = e4.x + ed4.x; l0 = v > 0.f ? v : 0.2f*v;
      v = e4.y + ed4.y; l1 = v > 0.f ? v : 0.2f*v;
      v = e4.z + ed4.z; l2 = v > 0.f ? v : 0.2f*v;
      v = e4.w + ed4.w; l3 = v > 0.f ? v : 0.2f*v;
    }
    float m0=l0, m1=l1, m2=l2, m3=l3;
    #pragma unroll
    for (int o=1;o<64;o<<=1){
      m0 = fmaxf(m0, __shfl_xor(m0,o,64));
      m1 = fmaxf(m1, __shfl_xor(m1,o,64));
      m2 = fmaxf(m2, __shfl_xor(m2,o,64));
      m3 = fmaxf(m3, __shfl_xor(m3,o,64));
    }
    float p0 = (lane<deg) ? __expf(l0-m0) : 0.f;
    float p1 = (lane<deg) ? __expf(l1-m1) : 0.f;
    float p2 = (lane<deg) ? __expf(l2-m2) : 0.f;
    float p3 = (lane<deg) ? __expf(l3-m3) : 0.f;
    float d0=p0, d1=p1, d2=p2, d3=p3;
    #pragma unroll
    for (int o=1;o<64;o<<=1){
      d0 += __shfl_xor(d0,o,64);
      d1 += __shfl_xor(d1,o,64);
      d2 += __shfl_xor(d2,o,64);
      d3 += __shfl_xor(d3,o,64);
    }
    float al0 = p0 * (1.f/(d0+1e-16f));
    float al1 = p1 * (1.f/(d1+1e-16f));
    float al2 = p2 * (1.f/(d2+1e-16f));
    float al3 = p3 * (1.f/(d3+1e-16f));

    int j = 0;
    for (; j + 4 <= deg; j += 4){
      int sA = __shfl(src, j, 64);
      int sB = __shfl(src, j+1, 64);
      int sC = __shfl(src, j+2, 64);
      int sD = __shfl(src, j+3, 64);
      float a0A = __shfl(al0, j, 64),   a1A = __shfl(al1, j, 64);
      float a2A = __shfl(al2, j, 64),   a3A = __shfl(al3, j, 64);
      float a0B = __shfl(al0, j+1, 64), a1B = __shfl(al1, j+1, 64);
      float a2B = __shfl(al2, j+1, 64), a3B = __shfl(al3, j+1, 64);
      float a0C = __shfl(al0, j+2, 64), a1C = __shfl(al1, j+2, 64);
      float a2C = __shfl(al2, j+2, 64), a3C = __shfl(al3, j+2, 64);
      float a0D = __shfl(al0, j+3, 64), a1D = __shfl(al1, j+3, 64);
      float a2D = __shfl(al2, j+3, 64), a3D = __shfl(al3, j+3, 64);
      float aA = (h==0) ? a0A : ((h==1) ? a1A : ((h==2) ? a2A : a3A));
      float aB = (h==0) ? a0B : ((h==1) ? a1B : ((h==2) ? a2B : a3B));
      float aC = (h==0) ? a0C : ((h==1) ? a1C : ((h==2) ? a2C : a3C));
      float aD = (h==0) ? a0D : ((h==1) ? a1D : ((h==2) ? a2D : a3D));
      const unsigned short* rA = xwu + (size_t)sA*1024 + cb;
      const unsigned short* rB = xwu + (size_t)sB*1024 + cb;
      const unsigned short* rC = xwu + (size_t)sC*1024 + cb;
      const unsigned short* rD = xwu + (size_t)sD*1024 + cb;
      ushort8v uA0 = *(const ushort8v*)(rA);
      ushort8v uA1 = *(const ushort8v*)(rA+8);
      ushort8v uB0 = *(const ushort8v*)(rB);
      ushort8v uB1 = *(const ushort8v*)(rB+8);
      ushort8v uC0 = *(const ushort8v*)(rC);
      ushort8v uC1 = *(const ushort8v*)(rC+8);
      ushort8v uD0 = *(const ushort8v*)(rD);
      ushort8v uD1 = *(const ushort8v*)(rD+8);
      #pragma unroll
      for (int c=0;c<8;c++){ acc[c]   += aA*raw2f(uA0[c]); acc[8+c] += aA*raw2f(uA1[c]); }
      #pragma unroll
      for (int c=0;c<8;c++){ acc[c]   += aB*raw2f(uB0[c]); acc[8+c] += aB*raw2f(uB1[c]); }
      #pragma unroll
      for (int c=0;c<8;c++){ acc[c]   += aC*raw2f(uC0[c]); acc[8+c] += aC*raw2f(uC1[c]); }
      #pragma unroll
      for (int c=0;c<8;c++){ acc[c]   += aD*raw2f(uD0[c]); acc[8+c] += aD*raw2f(uD1[c]); }
    }
    for (; j < deg; j++){
      int s = __shfl(src, j, 64);
      float a0j = __shfl(al0, j, 64);
      float a1j = __shfl(al1, j, 64);
      float a2j = __shfl(al2, j, 64);
      float a3j = __shfl(al3, j, 64);
      float aj = (h==0) ? a0j : ((h==1) ? a1j : ((h==2) ? a2j : a3j));
      const unsigned short* row = xwu + (size_t)s*1024 + cb;
      ushort8v u0 = *(const ushort8v*)(row);
      ushort8v u1 = *(const ushort8v*)(row+8);
      #pragma unroll
      for (int c=0;c<8;c++){ acc[c] += aj*raw2f(u0[c]); acc[8+c] += aj*raw2f(u1[c]); }
    }
  } else {
    float edh = (h==0) ? ed4.x : ((h==1) ? ed4.y : ((h==2) ? ed4.z : ed4.w));
    float m = -1e30f;
    for (int e=e0;e<e1;e++){
      float v = es[col[e]*4 + h] + edh;
      v = v > 0.f ? v : 0.2f*v;
      m = fmaxf(m, v);
    }
    float den = 0.f;
    for (int e=e0;e<e1;e++){
      float v = es[col[e]*4 + h] + edh;
      v = v > 0.f ? v : 0.2f*v;
      den += __expf(v - m);
    }
    float rd = 1.f/(den + 1e-16f);
    for (int e=e0;e<e1;e++){
      int s = col[e];
      float v = es[s*4 + h] + edh;
      v = v > 0.f ? v : 0.2f*v;
      float aj = __expf(v - m) * rd;
      const unsigned short* row = xwu + (size_t)s*1024 + cb;
      ushort8v u0 = *(const ushort8v*)(row);
      ushort8v u1 = *(const ushort8v*)(row+8);
      #pragma unroll
      for (int c=0;c<8;c++){ acc[c] += aj*raw2f(u0[c]); acc[8+c] += aj*raw2f(u1[c]); }
    }
  }

  #pragma unroll
  for (int c=0;c<16;c++) acc[c] += bias[cb+c];
  float s1 = 0.f, s2 = 0.f;
  #pragma unroll
  for (int c=0;c<16;c++){ s1 += acc[c]; s2 += acc[c]*acc[c]; }
  #pragma unroll
  for (int o=1;o<64;o<<=1){
    s1 += __shfl_xor(s1,o,64);
    s2 += __shfl_xor(s2,o,64);
  }
  float mu  = s1 * (1.f/1024.f);
  float var = s2 * (1.f/1024.f) - mu*mu;
  float rstd = rsqrtf(fmaxf(var, 0.f) + 1e-5f);

  ushort4 o4[4];
  #pragma unroll
  for (int q=0;q<4;q++){
    float v0 = (acc[q*4+0]-mu)*rstd*gam[cb+q*4+0] + bet[cb+q*4+0];
    float v1 = (acc[q*4+1]-mu)*rstd*gam[cb+q*4+1] + bet[cb+q*4+1];
    float v2 = (acc[q*4+2]-mu)*rstd*gam[cb+q*4+2] + bet[cb+q*4+2];
    float v3 = (acc[q*4+3]-mu)*rstd*gam[cb+q*4+3] + bet[cb+q*4+3];
    v0 = v0 > 0.f ? v0 : (__expf(v0)-1.f);
    v1 = v1 > 0.f ? v1 : (__expf(v1)-1.f);
    v2 = v2 > 0.f ? v2 : (__expf(v2)-1.f);
    v3 = v3 > 0.f ? v3 : (__expf(v3)-1.f);
    o4[q].x = f2raw(v0); o4[q].y = f2raw(v1); o4[q].z = f2raw(v2); o4[q].w = f2raw(v3);
  }
  unsigned short* dst = (unsigned short*)act + (size_t)n*1024 + cb;
  *(ushort4*)(dst)    = o4[0];
  *(ushort4*)(dst+4)  = o4[1];
  *(ushort4*)(dst+8)  = o4[2];
  *(ushort4*)(dst+12) = o4[3];

  // zero next layer's logit slots for this node (exclusive ownership; read next dispatch)
  if (lane < zn){ esz[n*zn + lane] = 0.f; edz[n*zn + lane] = 0.f; }
}

// ---------------- wave-per-node layer-3: softmax + aggregate + bias -> fp32 out (H=1) ----------------
__global__ __launch_bounds__(128) void k_agg3(const int* __restrict__ rp, const int* __restrict__ col,
    const bf16* __restrict__ xw, const float* __restrict__ es, const float* __restrict__ ed,
    const float* __restrict__ bias, float* __restrict__ out){
  int wv = threadIdx.x >> 6, lane = threadIdx.x & 63;
  int n = blockIdx.x*2 + wv;
  int cb = lane * 8;
  int e0 = rp[n], e1 = rp[n+1], deg = e1 - e0;
  float edv = ed[n];
  const unsigned short* xwu = (const unsigned short*)xw;

  float acc[8];
  #pragma unroll
  for (int c=0;c<8;c++) acc[c]=0.f;

  if (deg <= 64){
    int src = 0;
    float l = -1e30f;
    if (lane < deg){
      src = col[e0 + lane];
      float v = es[src] + edv;
      l = v > 0.f ? v : 0.2f*v;
    }
    float m = l;
    #pragma unroll
    for (int o=1;o<64;o<<=1) m = fmaxf(m, __shfl_xor(m,o,64));
    float p = (lane<deg) ? __expf(l-m) : 0.f;
    float d = p;
    #pragma unroll
    for (int o=1;o<64;o<<=1) d += __shfl_xor(d,o,64);
    float al = p * (1.f/(d+1e-16f));

    int j = 0;
    for (; j + 4 <= deg; j += 4){
      int sA = __shfl(src, j, 64);
      int sB = __shfl(src, j+1, 64);
      int sC = __shfl(src, j+2, 64);
      int sD = __shfl(src, j+3, 64);
      float aA = __shfl(al, j, 64);
      float aB = __shfl(al, j+1, 64);
      float aC = __shfl(al, j+2, 64);
      float aD = __shfl(al, j+3, 64);
      const unsigned short* rA = xwu + (size_t)sA*512 + cb;
      const unsigned short* rB = xwu + (size_t)sB*512 + cb;
      const unsigned short* rC = xwu + (size_t)sC*512 + cb;
      const unsigned short* rD = xwu + (size_t)sD*512 + cb;
      ushort8v uA = *(const ushort8v*)(rA);
      ushort8v uB = *(const ushort8v*)(rB);
      ushort8v uC = *(const ushort8v*)(rC);
      ushort8v uD = *(const ushort8v*)(rD);
      #pragma unroll
      for (int c=0;c<8;c++) acc[c] += aA*raw2f(uA[c]);
      #pragma unroll
      for (int c=0;c<8;c++) acc[c] += aB*raw2f(uB[c]);
      #pragma unroll
      for (int c=0;c<8;c++) acc[c] += aC*raw2f(uC[c]);
      #pragma unroll
      for (int c=0;c<8;c++) acc[c] += aD*raw2f(uD[c]);
    }
    for (; j < deg; j++){
      int s = __shfl(src, j, 64);
      float aj = __shfl(al, j, 64);
      const unsigned short* row = xwu + (size_t)s*512 + cb;
      ushort8v u = *(const ushort8v*)(row);
      #pragma unroll
      for (int c=0;c<8;c++) acc[c] += aj*raw2f(u[c]);
    }
  } else {
    float m = -1e30f;
    for (int e=e0;e<e1;e++){
      float v = es[col[e]] + edv;
      v = v > 0.f ? v : 0.2f*v;
      m = fmaxf(m, v);
    }
    float den = 0.f;
    for (int e=e0;e<e1;e++){
      float v = es[col[e]] + edv;
      v = v > 0.f ? v : 0.2f*v;
      den += __expf(v - m);
    }
    float rd = 1.f/(den + 1e-16f);
    for (int e=e0;e<e1;e++){
      int s = col[e];
      float v = es[s] + edv;
      v = v > 0.f ? v : 0.2f*v;
      float aj = __expf(v - m) * rd;
      const unsigned short* row = xwu + (size_t)s*512 + cb;
      ushort8v u = *(const ushort8v*)(row);
      #pragma unroll
      for (int c=0;c<8;c++) acc[c] += aj*raw2f(u[c]);
    }
  }
  float* dst = out + (size_t)n*512 + cb;
  #pragma unroll
  for (int c=0;c<8;c++) dst[c] = acc[c] + bias[cb+c];
}

__global__ void k_wssmall(float* __restrict__ out, float code){
  if (threadIdx.x == 0) out[0] = code;
}

// ---------------- launch ----------------
extern "C" void kernel_launch(void* const* d_in, const int* in_sizes, int n_in,
                              void* d_out, int out_size, void* d_ws, size_t ws_size,
                              hipStream_t stream){
  float* out = (float*)d_out;
  char* ws = (char*)d_ws;

  static const int EXP_SZ[18] = {2560000, 320000, 131072, 1024,1024,1024,1024,1024,
                                 1048576, 1024,1024,1024,1024,1024,
                                 524288, 512,512,512};
  if (n_in != 18){ k_wssmall<<<1,64,0,stream>>>(out, 500.0f*301.0f); return; }
  for (int i = 0; i < 18; i++)
    if (in_sizes[i] != EXP_SZ[i]){ k_wssmall<<<1,64,0,stream>>>(out, 500.0f*302.0f); return; }
  if (out_size != NN*512){ k_wssmall<<<1,64,0,stream>>>(out, 500.0f*303.0f); return; }
  const size_t NEED = 93215360;
  if (ws_size < NEED){ k_wssmall<<<1,64,0,stream>>>(out, 500.0f*304.0f); return; }

  // ---- workspace layout ----
  bf16* xw    = (bf16*) (ws);                    // 40,960,000 (first 80KB doubles as CSR 'counts')
  int*  cnt   = (int*)  (ws);                    // aliases xw: counts, live prep->scan
  bf16* act   = (bf16*) (ws + 40960000);         // -> 81,920,000 (first 80KB doubles as CSR 'cursor')
  int*  cursor= (int*)  (ws + 40960000);         // aliases act: live scan->scatter
  bf16* Xc    = (bf16*) (ws + 81920000);         // -> 87,040,000 (dead after gemm1)
  float* esC  = (float*)(ws + 81920000);         // aliases Xc: 80,000 B (layer-3 logits, H=1)
  float* edC  = (float*)(ws + 82000000);         // aliases Xc: 80,000 B
  bf16* Wt1   = (bf16*) (ws + 87040000);         // -> 87,302,144
  bf16* Wt2   = (bf16*) (ws + 87302144);         // -> 89,399,296
  bf16* Wt3   = (bf16*) (ws + 89399296);         // -> 90,447,872
  float* prm  = (float*)(ws + 90447872);         // -> 90,494,976
  int*  eic   = (int*)  (ws + 90495232);         // -> 91,775,232 (dead after scatter)
  float* esB  = (float*)(ws + 90495232);         // aliases eic: 320,000 B (layer-2 logits)
  float* edB  = (float*)(ws + 90815232);         // aliases eic: 320,000 B
  float* esA  = (float*)(ws + 91775232);         // -> 92,095,232 (layer-1 logits)
  float* edA  = (float*)(ws + 92095232);         // -> 92,415,232
  int*  rp    = (int*)  (ws + 92415232);         // -> 92,495,360
  int*  col   = (int*)  (ws + 92495360);         // -> 93,215,360

  float *as1=prm+0, *ad1=prm+1024, *b1=prm+2048, *lg1=prm+3072, *lb1=prm+4096;
  float *as2=prm+5120, *ad2=prm+6144, *b2=prm+7168, *lg2=prm+8192, *lb2=prm+9216;
  float *as3=prm+10240, *ad3=prm+10752, *b3=prm+11264;

  const int TB = 256;
  int gbE = (EE + TB - 1)/TB;

  // ---- fused prep ----
  {
    PrepArgs A;
    A.xraw = d_in[0]; A.Xc = Xc;
    A.w1raw = d_in[2]; A.Wt1 = Wt1;
    A.w2raw = d_in[8]; A.Wt2 = Wt2;
    A.w3raw = d_in[14]; A.Wt3 = Wt3;
    A.eiraw = (const int*)d_in[1]; A.eic = eic;
    const int idx[13] = {3,4,5,6,7, 9,10,11,12,13, 15,16,17};
    const int off[13] = {0,1024,2048,3072,4096, 5120,6144,7168,8192,9216, 10240,10752,11264};
    const int nn [13] = {1024,1024,1024,1024,1024, 1024,1024,1024,1024,1024, 512,512,512};
    for (int i=0;i<13;i++){ A.p13.src[i]=d_in[idx[i]]; A.p13.off[i]=off[i]; A.p13.n[i]=nn[i]; }
    A.prm = prm; A.counts = cnt; A.esA = esA; A.edA = edA;
    k_prep<<<13006 + 313, TB, 0, stream>>>(A);
  }

  // ---- CSR ----
  k_hist<<<gbE, TB, 0, stream>>>(eic, cnt);
  k_scan<<<1, 1024, 0, stream>>>(cnt, rp, cursor, col);
  k_scatter<<<gbE, TB, 0, stream>>>(eic, cursor, col);

  const int RB = (NN + 63)/64;                    // 313 row-bands of 64 (layer-1 kernel)
  const int R8 = ((RB + 7)/8)*8;                  // 320 (padded, guard in kernel)
  dim3 g1(1024/128, R8);

  const int RB2 = ((((NN + 255)/256) + 7)/8)*8;   // 79 bands of 256 -> pad 80
  dim3 g2(1024/256, RB2);                         // 4 x 80 = 320 blocks (316 valid)
  dim3 g3(512/256,  RB2);                         // 2 x 80 = 160 blocks (158 valid)

  // ---- layer 1 (K=128): proven 64x128 kernel ----
  k_gemm_mfma<<<g1, TB, 0, stream>>>(Xc, Wt1, xw, as1, ad1, esA, edA, 128, 1024, 256, 4);
  k_aggln<<<NN/2, 128, 0, stream>>>(rp, col, xw, esA, edA, b1, lg1, lb1, act, esB, edB, 4);

  // ---- layer 2 (K=1024): 8-phase 256^2 ----
  k_gemm_8p<<<g2, 512, 0, stream>>>(act, Wt2, xw, as2, ad2, esB, edB, 1024, 1024, 256, 4);
  k_aggln<<<NN/2, 128, 0, stream>>>(rp, col, xw, esB, edB, b2, lg2, lb2, act, esC, edC, 1);

  // ---- layer 3 (K=1024, M=512): 8-phase 256^2 ----
  k_gemm_8p<<<g3, 512, 0, stream>>>(act, Wt3, xw, as3, ad3, esC, edC, 1024, 512, 512, 1);
  k_agg3<<<NN/2, 128, 0, stream>>>(rp, col, xw, esC, edC, b3, out);
}

// Round 7
// 441.998 us; speedup vs baseline: 1.2602x; 1.2602x over previous
//
#include <hip/hip_runtime.h>
#include <hip/hip_bf16.h>

typedef __hip_bfloat16 bf16;
typedef __attribute__((ext_vector_type(8))) short short8;
typedef __attribute__((ext_vector_type(8))) unsigned short ushort8v;
typedef __attribute__((ext_vector_type(4))) float float4v;

#define NN 20000
#define EE 160000
#define ET (NN + EE)

__device__ __forceinline__ float bf2f(bf16 v){ return __bfloat162float(v); }
__device__ __forceinline__ float raw2f(unsigned short u){ return __uint_as_float(((unsigned)u) << 16); }
__device__ __forceinline__ unsigned short f2raw(float f){
  bf16 h = __float2bfloat16(f);
  return *(unsigned short*)&h;
}

// ---------------- inline dtype detection (per-wave ballot; all waves agree) ----------------
__device__ __forceinline__ int detect_f32(const void* raw, int nwords, int lane){
  unsigned v = ((const unsigned*)raw)[lane % nwords];
  int e8 = (v >> 7) & 0xFF;
  int looks = (e8 >= 100 && e8 <= 140) ? 1 : 0;
  unsigned long long mz = __ballot(v == 0u);
  unsigned long long ml = __ballot(looks);
  int nz = __popcll(mz);
  int nonz = 64 - nz;
  int nl = __popcll(ml);
  return (nonz > 0 && 2*nl >= nonz) ? 0 : 1;
}

__device__ __forceinline__ int detect_i64(const int* eiraw, int lane){
  int odd = eiraw[2*lane + 1];
  unsigned long long m2 = __ballot(odd != 0);
  return (m2 == 0ULL) ? 1 : 0;
}

// ---------------- fused preprocessing kernel ----------------
struct P13 { const void* src[13]; int off[13]; int n[13]; };
struct PrepArgs {
  const void* xraw; bf16* Xc;
  const void* w1raw; bf16* Wt1;
  const void* w2raw; bf16* Wt2;
  const void* w3raw; bf16* Wt3;
  const int* eiraw; int* eic;
  P13 p13; float* prm;
  int* counts;
  float* esA; float* edA;
};

__device__ __forceinline__ void do_transpose(float (*tile)[33], const void* raw,
    bf16* wt, int K, int M, int f, int bx, int by, int t){
  int kb = by*32, mb = bx*32;
  int tx = t & 31, ty = t >> 5;   // 32 x 8
  for (int r = 0; r < 4; r++){
    int k = kb + ty + r*8;
    int m = mb + tx;
    float v = f ? ((const float*)raw)[(size_t)k*M+m] : bf2f(((const bf16*)raw)[(size_t)k*M+m]);
    tile[ty + r*8][tx] = v;
  }
  __syncthreads();
  for (int r = 0; r < 4; r++){
    int m = mb + ty + r*8;
    int k = kb + tx;
    wt[(size_t)m*K + k] = __float2bfloat16(tile[tx][ty + r*8]);
  }
}

__global__ __launch_bounds__(256) void k_prep(PrepArgs A){
  __shared__ float tile[32][33];
  int b = blockIdx.x, t = threadIdx.x;
  int lane = t & 63;
  if (b < 10000){                                 // cvt X -> bf16
    int f = detect_f32(A.xraw, NN*128/2, lane);
    int i = b*256 + t;
    if (f) A.Xc[i] = __float2bfloat16(((const float*)A.xraw)[i]);
    else   A.Xc[i] = ((const bf16*)A.xraw)[i];
  } else if (b < 10128){                          // transpose W1 [128][1024] -> [1024][128]
    int f = detect_f32(A.w1raw, 128*1024/2, lane);
    int r = b - 10000;
    do_transpose(tile, A.w1raw, A.Wt1, 128, 1024, f, r & 31, r >> 5, t);
  } else if (b < 11152){                          // transpose W2 [1024][1024]
    int f = detect_f32(A.w2raw, 1024*1024/2, lane);
    int r = b - 10128;
    do_transpose(tile, A.w2raw, A.Wt2, 1024, 1024, f, r & 31, r >> 5, t);
  } else if (b < 11664){                          // transpose W3 [1024][512] -> [512][1024]
    int f = detect_f32(A.w3raw, 1024*512/2, lane);
    int r = b - 11152;
    do_transpose(tile, A.w3raw, A.Wt3, 1024, 512, f, r & 15, r >> 4, t);
  } else if (b < 12914){                          // cvte
    int f64 = detect_i64(A.eiraw, lane);
    int i = (b - 11664)*256 + t;
    if (i < 2*EE) A.eic[i] = f64 ? A.eiraw[2*i] : A.eiraw[i];
  } else if (b < 12927){                          // params -> fp32
    int pb = b - 12914;
    const void* s = A.p13.src[pb];
    int n = A.p13.n[pb];
    int f = detect_f32(s, n/2, lane);
    float* d = A.prm + A.p13.off[pb];
    for (int i = t; i < n; i += 256)
      d[i] = f ? ((const float*)s)[i] : bf2f(((const bf16*)s)[i]);
  } else if (b < 13006){                          // init_counts
    int i = (b - 12927)*256 + t;
    if (i < NN) A.counts[i] = 1;
  } else {                                        // zero esA/edA (NN*4 floats each)
    int i = (b - 13006)*256 + t;
    if (i < NN*4){ A.esA[i] = 0.f; A.edA[i] = 0.f; }
  }
}

// ---------------- CSR build ----------------
__global__ void k_hist(const int* __restrict__ ei, int* __restrict__ counts){
  int e = blockIdx.x*256 + threadIdx.x;
  if (e < EE){
    int d = ei[EE + e];
    if (d >= 0 && d < NN) atomicAdd(&counts[d], 1);
  }
}

// Round-7: hierarchical scan replaces the single-block k_scan (1 CU serially scanning 20000
// counts ~= 10-17us). 3 kernels ~4-6us total. Same segment layout: self loop at head,
// cursor = p+1. bsum/boff (20 ints each) live in the 256B gap after prm.
__global__ __launch_bounds__(1024) void k_scanA(const int* __restrict__ counts, int* __restrict__ rp,
    int* __restrict__ bsum){
  __shared__ int wsum[16];
  int b = blockIdx.x, t = threadIdx.x, lane = t & 63, wv = t >> 6;
  int i = b*1024 + t;
  int v = (i < NN) ? counts[i] : 0;
  int x = v;
  #pragma unroll
  for (int o = 1; o < 64; o <<= 1){
    int y = __shfl_up(x, o, 64);
    if (lane >= o) x += y;
  }
  if (lane == 63) wsum[wv] = x;
  __syncthreads();
  if (wv == 0 && lane < 16){
    int w = wsum[lane];
    #pragma unroll
    for (int o = 1; o < 16; o <<= 1){
      int y = __shfl_up(w, o, 16);
      if (lane >= o) w += y;
    }
    wsum[lane] = w;
  }
  __syncthreads();
  int wpre = (wv > 0) ? wsum[wv-1] : 0;
  if (i < NN) rp[i] = wpre + x - v;      // block-local exclusive
  if (t == 1023) bsum[b] = wsum[15];     // block total
}

__global__ void k_scanB(const int* __restrict__ bsum, int* __restrict__ boff,
    int* __restrict__ rp, int nb){
  int t = threadIdx.x;                   // 64 threads, nb <= 64
  int v = (t < nb) ? bsum[t] : 0;
  int x = v;
  #pragma unroll
  for (int o = 1; o < 64; o <<= 1){
    int y = __shfl_up(x, o, 64);
    if (t >= o) x += y;
  }
  if (t < nb) boff[t] = x - v;           // exclusive block offsets
  if (t == 63) rp[NN] = x;               // grand total
}

__global__ __launch_bounds__(1024) void k_scanC(int* __restrict__ rp, const int* __restrict__ boff,
    int* __restrict__ cursor, int* __restrict__ col){
  int i = blockIdx.x*1024 + threadIdx.x;
  if (i < NN){
    int p = boff[blockIdx.x] + rp[i];
    rp[i] = p;
    col[p] = i;                          // self loop at segment head
    cursor[i] = p + 1;
  }
}

__global__ void k_scatter(const int* __restrict__ ei, int* __restrict__ cursor, int* __restrict__ col){
  int e = blockIdx.x*256 + threadIdx.x;
  if (e < EE){
    int s = ei[e], d = ei[EE + e];
    if (d >= 0 && d < NN){
      int pos = atomicAdd(&cursor[d], 1);
      col[pos] = s;
    }
  }
}

// ---------------- MFMA GEMM: 64x128 tile, BK=64, XOR-swizzled LDS, fused fp32 es/ed ----------------
// ROUND-0 STRUCTURE — FINAL. Four structural alternatives measured and all lost at these shapes
// (M=20000 tall-skinny, K=1024): r1 128^2 tile 94us (occ 23%); r2 dbuf+drain 89us; r3 dbuf+counted
// vmcnt 85.6us (occ 26%); r6 8-phase 256^2 port 158us (1 blk/CU, MfmaUtil 10%). This single-buffer
// 64x128 wins on block-TLP: ~3.3 blocks/CU, cross-block waves hide the per-K-step barrier drain.
__global__ __launch_bounds__(256) void k_gemm_mfma(
    const bf16* __restrict__ X, const bf16* __restrict__ Wt, bf16* __restrict__ Y,
    const float* __restrict__ as_, const float* __restrict__ ad_,
    float* __restrict__ es, float* __restrict__ ed,
    int K, int M, int C, int H)
{
  __shared__ bf16 Xs[64*64];    // 8 KB
  __shared__ bf16 Bs[128*64];   // 16 KB
  int ncols = gridDim.x;
  int bid = blockIdx.y * ncols + blockIdx.x;
  int xcd  = bid & 7;
  int rest = bid >> 3;
  int colb = rest % ncols;
  int rowb = xcd + 8 * (rest / ncols);
  int r0 = rowb * 64;
  if (r0 >= NN) return;
  int c0 = colb * 128;

  int tid  = threadIdx.x;
  int wave = tid >> 6, lane = tid & 63;
  int quad = lane >> 4, l15 = lane & 15;
  int wr = (wave >> 1) * 32;     // 2 row-groups of 32
  int wc = (wave & 1) * 64;      // 2 col-groups of 64
  int sw = l15 & 7;

  float4v acc[2][4];
  #pragma unroll
  for (int i=0;i<2;i++)
    #pragma unroll
    for (int j=0;j<4;j++)
      acc[i][j] = (float4v){0.f,0.f,0.f,0.f};

  for (int k0 = 0; k0 < K; k0 += 64){
    #pragma unroll
    for (int i = 0; i < 2; i++){            // Xs: 512 chunks of 16B
      int ch = i*256 + tid;
      int row = ch >> 3, kl = ch & 7;
      int kg = kl ^ (row & 7);
      const bf16* gx = X + (size_t)(r0 + row)*K + k0 + kg*8;
      __builtin_amdgcn_global_load_lds(
        (const __attribute__((address_space(1))) unsigned int*)gx,
        (__attribute__((address_space(3))) unsigned int*)(Xs + ch*8), 16, 0, 0);
    }
    #pragma unroll
    for (int i = 0; i < 4; i++){            // Bs: 1024 chunks of 16B
      int ch = i*256 + tid;
      int row = ch >> 3, kl = ch & 7;
      int kg = kl ^ (row & 7);
      const bf16* gb = Wt + (size_t)(c0 + row)*K + k0 + kg*8;
      __builtin_amdgcn_global_load_lds(
        (const __attribute__((address_space(1))) unsigned int*)gb,
        (__attribute__((address_space(3))) unsigned int*)(Bs + ch*8), 16, 0, 0);
    }
    __syncthreads();

    #pragma unroll
    for (int kk = 0; kk < 2; kk++){         // two 32-wide K slices, in order (bit-identical accum)
      int kp = quad + kk*4;
      short8 af[2], bfr[4];
      #pragma unroll
      for (int i = 0; i < 2; i++){
        int r = wr + i*16 + l15;
        af[i] = *(const short8*)(Xs + ((size_t)r*8 + (kp ^ sw))*8);
      }
      #pragma unroll
      for (int j = 0; j < 4; j++){
        int r = wc + j*16 + l15;
        bfr[j] = *(const short8*)(Bs + ((size_t)r*8 + (kp ^ sw))*8);
      }
      #pragma unroll
      for (int i = 0; i < 2; i++)
        #pragma unroll
        for (int j = 0; j < 4; j++)
          acc[i][j] = __builtin_amdgcn_mfma_f32_16x16x32_bf16(af[i], bfr[j], acc[i][j], 0, 0, 0);
    }
    __syncthreads();
  }

  int h = c0 / C;
  float asv[4], adv[4];
  #pragma unroll
  for (int j = 0; j < 4; j++){
    int colj = c0 + wc + j*16 + l15;
    asv[j] = as_[colj]; adv[j] = ad_[colj];
  }
  #pragma unroll
  for (int i = 0; i < 2; i++){
    int rbase = r0 + wr + i*16 + quad*4;
    #pragma unroll
    for (int rg = 0; rg < 4; rg++){
      int row = rbase + rg;
      bool ok = (row < NN);
      float pe = 0.f, pd = 0.f;
      #pragma unroll
      for (int j = 0; j < 4; j++){
        float v = acc[i][j][rg];
        int colj = c0 + wc + j*16 + l15;
        if (ok) Y[(size_t)row*M + colj] = __float2bfloat16(v);
        pe += v * asv[j];
        pd += v * adv[j];
      }
      #pragma unroll
      for (int o = 1; o < 16; o <<= 1){
        pe += __shfl_xor(pe, o, 64);
        pd += __shfl_xor(pd, o, 64);
      }
      if (ok && l15 == 0){
        atomicAdd(&es[row*H + h], pe);
        atomicAdd(&ed[row*H + h], pd);
      }
    }
  }
}

// ---------------- wave-per-node softmax+aggregate+bias+LN+ELU (layers 1,2; H=4) ----------------
// r5 state: 128-thr blocks (2 waves) for fine-grain backfill of degree imbalance (+8us vs 256).
// r4 showed load-depth unrolling is neutral -> at the L3 random-2KB-gather floor (~5-6 TB/s eff).
__global__ __launch_bounds__(128) void k_aggln(const int* __restrict__ rp, const int* __restrict__ col,
    const bf16* __restrict__ xw, const float* __restrict__ es, const float* __restrict__ ed,
    const float* __restrict__ bias, const float* __restrict__ gam, const float* __restrict__ bet,
    bf16* __restrict__ act, float* __restrict__ esz, float* __restrict__ edz, int zn){
  int wv = threadIdx.x >> 6, lane = threadIdx.x & 63;
  int n = blockIdx.x*2 + wv;              // NN % 2 == 0
  int h = lane >> 4;
  int cb = lane * 16;
  int e0 = rp[n], e1 = rp[n+1], deg = e1 - e0;
  float4 ed4 = *(const float4*)&ed[n*4];
  const unsigned short* xwu = (const unsigned short*)xw;

  float acc[16];
  #pragma unroll
  for (int c=0;c<16;c++) acc[c]=0.f;

  if (deg <= 64){
    int src = 0;
    float l0=-1e30f, l1=-1e30f, l2=-1e30f, l3=-1e30f;
    if (lane < deg){
      src = col[e0 + lane];
      float4 e4 = *(const float4*)&es[src*4];
      float v;
      v = e4.x + ed4.x; l0 = v > 0.f ? v : 0.2f*v;
      v = e4.y + ed4.y; l1 = v > 0.f ? v : 0.2f*v;
      v = e4.z + ed4.z; l2 = v > 0.f ? v : 0.2f*v;
      v = e4.w + ed4.w; l3 = v > 0.f ? v : 0.2f*v;
    }
    float m0=l0, m1=l1, m2=l2, m3=l3;
    #pragma unroll
    for (int o=1;o<64;o<<=1){
      m0 = fmaxf(m0, __shfl_xor(m0,o,64));
      m1 = fmaxf(m1, __shfl_xor(m1,o,64));
      m2 = fmaxf(m2, __shfl_xor(m2,o,64));
      m3 = fmaxf(m3, __shfl_xor(m3,o,64));
    }
    float p0 = (lane<deg) ? __expf(l0-m0) : 0.f;
    float p1 = (lane<deg) ? __expf(l1-m1) : 0.f;
    float p2 = (lane<deg) ? __expf(l2-m2) : 0.f;
    float p3 = (lane<deg) ? __expf(l3-m3) : 0.f;
    float d0=p0, d1=p1, d2=p2, d3=p3;
    #pragma unroll
    for (int o=1;o<64;o<<=1){
      d0 += __shfl_xor(d0,o,64);
      d1 += __shfl_xor(d1,o,64);
      d2 += __shfl_xor(d2,o,64);
      d3 += __shfl_xor(d3,o,64);
    }
    float al0 = p0 * (1.f/(d0+1e-16f));
    float al1 = p1 * (1.f/(d1+1e-16f));
    float al2 = p2 * (1.f/(d2+1e-16f));
    float al3 = p3 * (1.f/(d3+1e-16f));

    int j = 0;
    for (; j + 4 <= deg; j += 4){
      int sA = __shfl(src, j, 64);
      int sB = __shfl(src, j+1, 64);
      int sC = __shfl(src, j+2, 64);
      int sD = __shfl(src, j+3, 64);
      float a0A = __shfl(al0, j, 64),   a1A = __shfl(al1, j, 64);
      float a2A = __shfl(al2, j, 64),   a3A = __shfl(al3, j, 64);
      float a0B = __shfl(al0, j+1, 64), a1B = __shfl(al1, j+1, 64);
      float a2B = __shfl(al2, j+1, 64), a3B = __shfl(al3, j+1, 64);
      float a0C = __shfl(al0, j+2, 64), a1C = __shfl(al1, j+2, 64);
      float a2C = __shfl(al2, j+2, 64), a3C = __shfl(al3, j+2, 64);
      float a0D = __shfl(al0, j+3, 64), a1D = __shfl(al1, j+3, 64);
      float a2D = __shfl(al2, j+3, 64), a3D = __shfl(al3, j+3, 64);
      float aA = (h==0) ? a0A : ((h==1) ? a1A : ((h==2) ? a2A : a3A));
      float aB = (h==0) ? a0B : ((h==1) ? a1B : ((h==2) ? a2B : a3B));
      float aC = (h==0) ? a0C : ((h==1) ? a1C : ((h==2) ? a2C : a3C));
      float aD = (h==0) ? a0D : ((h==1) ? a1D : ((h==2) ? a2D : a3D));
      const unsigned short* rA = xwu + (size_t)sA*1024 + cb;
      const unsigned short* rB = xwu + (size_t)sB*1024 + cb;
      const unsigned short* rC = xwu + (size_t)sC*1024 + cb;
      const unsigned short* rD = xwu + (size_t)sD*1024 + cb;
      ushort8v uA0 = *(const ushort8v*)(rA);
      ushort8v uA1 = *(const ushort8v*)(rA+8);
      ushort8v uB0 = *(const ushort8v*)(rB);
      ushort8v uB1 = *(const ushort8v*)(rB+8);
      ushort8v uC0 = *(const ushort8v*)(rC);
      ushort8v uC1 = *(const ushort8v*)(rC+8);
      ushort8v uD0 = *(const ushort8v*)(rD);
      ushort8v uD1 = *(const ushort8v*)(rD+8);
      #pragma unroll
      for (int c=0;c<8;c++){ acc[c]   += aA*raw2f(uA0[c]); acc[8+c] += aA*raw2f(uA1[c]); }
      #pragma unroll
      for (int c=0;c<8;c++){ acc[c]   += aB*raw2f(uB0[c]); acc[8+c] += aB*raw2f(uB1[c]); }
      #pragma unroll
      for (int c=0;c<8;c++){ acc[c]   += aC*raw2f(uC0[c]); acc[8+c] += aC*raw2f(uC1[c]); }
      #pragma unroll
      for (int c=0;c<8;c++){ acc[c]   += aD*raw2f(uD0[c]); acc[8+c] += aD*raw2f(uD1[c]); }
    }
    for (; j < deg; j++){
      int s = __shfl(src, j, 64);
      float a0j = __shfl(al0, j, 64);
      float a1j = __shfl(al1, j, 64);
      float a2j = __shfl(al2, j, 64);
      float a3j = __shfl(al3, j, 64);
      float aj = (h==0) ? a0j : ((h==1) ? a1j : ((h==2) ? a2j : a3j));
      const unsigned short* row = xwu + (size_t)s*1024 + cb;
      ushort8v u0 = *(const ushort8v*)(row);
      ushort8v u1 = *(const ushort8v*)(row+8);
      #pragma unroll
      for (int c=0;c<8;c++){ acc[c] += aj*raw2f(u0[c]); acc[8+c] += aj*raw2f(u1[c]); }
    }
  } else {
    float edh = (h==0) ? ed4.x : ((h==1) ? ed4.y : ((h==2) ? ed4.z : ed4.w));
    float m = -1e30f;
    for (int e=e0;e<e1;e++){
      float v = es[col[e]*4 + h] + edh;
      v = v > 0.f ? v : 0.2f*v;
      m = fmaxf(m, v);
    }
    float den = 0.f;
    for (int e=e0;e<e1;e++){
      float v = es[col[e]*4 + h] + edh;
      v = v > 0.f ? v : 0.2f*v;
      den += __expf(v - m);
    }
    float rd = 1.f/(den + 1e-16f);
    for (int e=e0;e<e1;e++){
      int s = col[e];
      float v = es[s*4 + h] + edh;
      v = v > 0.f ? v : 0.2f*v;
      float aj = __expf(v - m) * rd;
      const unsigned short* row = xwu + (size_t)s*1024 + cb;
      ushort8v u0 = *(const ushort8v*)(row);
      ushort8v u1 = *(const ushort8v*)(row+8);
      #pragma unroll
      for (int c=0;c<8;c++){ acc[c] += aj*raw2f(u0[c]); acc[8+c] += aj*raw2f(u1[c]); }
    }
  }

  #pragma unroll
  for (int c=0;c<16;c++) acc[c] += bias[cb+c];
  float s1 = 0.f, s2 = 0.f;
  #pragma unroll
  for (int c=0;c<16;c++){ s1 += acc[c]; s2 += acc[c]*acc[c]; }
  #pragma unroll
  for (int o=1;o<64;o<<=1){
    s1 += __shfl_xor(s1,o,64);
    s2 += __shfl_xor(s2,o,64);
  }
  float mu  = s1 * (1.f/1024.f);
  float var = s2 * (1.f/1024.f) - mu*mu;
  float rstd = rsqrtf(fmaxf(var, 0.f) + 1e-5f);

  ushort4 o4[4];
  #pragma unroll
  for (int q=0;q<4;q++){
    float v0 = (acc[q*4+0]-mu)*rstd*gam[cb+q*4+0] + bet[cb+q*4+0];
    float v1 = (acc[q*4+1]-mu)*rstd*gam[cb+q*4+1] + bet[cb+q*4+1];
    float v2 = (acc[q*4+2]-mu)*rstd*gam[cb+q*4+2] + bet[cb+q*4+2];
    float v3 = (acc[q*4+3]-mu)*rstd*gam[cb+q*4+3] + bet[cb+q*4+3];
    v0 = v0 > 0.f ? v0 : (__expf(v0)-1.f);
    v1 = v1 > 0.f ? v1 : (__expf(v1)-1.f);
    v2 = v2 > 0.f ? v2 : (__expf(v2)-1.f);
    v3 = v3 > 0.f ? v3 : (__expf(v3)-1.f);
    o4[q].x = f2raw(v0); o4[q].y = f2raw(v1); o4[q].z = f2raw(v2); o4[q].w = f2raw(v3);
  }
  unsigned short* dst = (unsigned short*)act + (size_t)n*1024 + cb;
  *(ushort4*)(dst)    = o4[0];
  *(ushort4*)(dst+4)  = o4[1];
  *(ushort4*)(dst+8)  = o4[2];
  *(ushort4*)(dst+12) = o4[3];

  // zero next layer's logit slots for this node (exclusive ownership; read next dispatch)
  if (lane < zn){ esz[n*zn + lane] = 0.f; edz[n*zn + lane] = 0.f; }
}

// ---------------- wave-per-node layer-3: softmax + aggregate + bias -> fp32 out (H=1) ----------------
__global__ __launch_bounds__(128) void k_agg3(const int* __restrict__ rp, const int* __restrict__ col,
    const bf16* __restrict__ xw, const float* __restrict__ es, const float* __restrict__ ed,
    const float* __restrict__ bias, float* __restrict__ out){
  int wv = threadIdx.x >> 6, lane = threadIdx.x & 63;
  int n = blockIdx.x*2 + wv;
  int cb = lane * 8;
  int e0 = rp[n], e1 = rp[n+1], deg = e1 - e0;
  float edv = ed[n];
  const unsigned short* xwu = (const unsigned short*)xw;

  float acc[8];
  #pragma unroll
  for (int c=0;c<8;c++) acc[c]=0.f;

  if (deg <= 64){
    int src = 0;
    float l = -1e30f;
    if (lane < deg){
      src = col[e0 + lane];
      float v = es[src] + edv;
      l = v > 0.f ? v : 0.2f*v;
    }
    float m = l;
    #pragma unroll
    for (int o=1;o<64;o<<=1) m = fmaxf(m, __shfl_xor(m,o,64));
    float p = (lane<deg) ? __expf(l-m) : 0.f;
    float d = p;
    #pragma unroll
    for (int o=1;o<64;o<<=1) d += __shfl_xor(d,o,64);
    float al = p * (1.f/(d+1e-16f));

    int j = 0;
    for (; j + 4 <= deg; j += 4){
      int sA = __shfl(src, j, 64);
      int sB = __shfl(src, j+1, 64);
      int sC = __shfl(src, j+2, 64);
      int sD = __shfl(src, j+3, 64);
      float aA = __shfl(al, j, 64);
      float aB = __shfl(al, j+1, 64);
      float aC = __shfl(al, j+2, 64);
      float aD = __shfl(al, j+3, 64);
      const unsigned short* rA = xwu + (size_t)sA*512 + cb;
      const unsigned short* rB = xwu + (size_t)sB*512 + cb;
      const unsigned short* rC = xwu + (size_t)sC*512 + cb;
      const unsigned short* rD = xwu + (size_t)sD*512 + cb;
      ushort8v uA = *(const ushort8v*)(rA);
      ushort8v uB = *(const ushort8v*)(rB);
      ushort8v uC = *(const ushort8v*)(rC);
      ushort8v uD = *(const ushort8v*)(rD);
      #pragma unroll
      for (int c=0;c<8;c++) acc[c] += aA*raw2f(uA[c]);
      #pragma unroll
      for (int c=0;c<8;c++) acc[c] += aB*raw2f(uB[c]);
      #pragma unroll
      for (int c=0;c<8;c++) acc[c] += aC*raw2f(uC[c]);
      #pragma unroll
      for (int c=0;c<8;c++) acc[c] += aD*raw2f(uD[c]);
    }
    for (; j < deg; j++){
      int s = __shfl(src, j, 64);
      float aj = __shfl(al, j, 64);
      const unsigned short* row = xwu + (size_t)s*512 + cb;
      ushort8v u = *(const ushort8v*)(row);
      #pragma unroll
      for (int c=0;c<8;c++) acc[c] += aj*raw2f(u[c]);
    }
  } else {
    float m = -1e30f;
    for (int e=e0;e<e1;e++){
      float v = es[col[e]] + edv;
      v = v > 0.f ? v : 0.2f*v;
      m = fmaxf(m, v);
    }
    float den = 0.f;
    for (int e=e0;e<e1;e++){
      float v = es[col[e]] + edv;
      v = v > 0.f ? v : 0.2f*v;
      den += __expf(v - m);
    }
    float rd = 1.f/(den + 1e-16f);
    for (int e=e0;e<e1;e++){
      int s = col[e];
      float v = es[s] + edv;
      v = v > 0.f ? v : 0.2f*v;
      float aj = __expf(v - m) * rd;
      const unsigned short* row = xwu + (size_t)s*512 + cb;
      ushort8v u = *(const ushort8v*)(row);
      #pragma unroll
      for (int c=0;c<8;c++) acc[c] += aj*raw2f(u[c]);
    }
  }
  float* dst = out + (size_t)n*512 + cb;
  #pragma unroll
  for (int c=0;c<8;c++) dst[c] = acc[c] + bias[cb+c];
}

__global__ void k_wssmall(float* __restrict__ out, float code){
  if (threadIdx.x == 0) out[0] = code;
}

// ---------------- launch ----------------
extern "C" void kernel_launch(void* const* d_in, const int* in_sizes, int n_in,
                              void* d_out, int out_size, void* d_ws, size_t ws_size,
                              hipStream_t stream){
  float* out = (float*)d_out;
  char* ws = (char*)d_ws;

  static const int EXP_SZ[18] = {2560000, 320000, 131072, 1024,1024,1024,1024,1024,
                                 1048576, 1024,1024,1024,1024,1024,
                                 524288, 512,512,512};
  if (n_in != 18){ k_wssmall<<<1,64,0,stream>>>(out, 500.0f*301.0f); return; }
  for (int i = 0; i < 18; i++)
    if (in_sizes[i] != EXP_SZ[i]){ k_wssmall<<<1,64,0,stream>>>(out, 500.0f*302.0f); return; }
  if (out_size != NN*512){ k_wssmall<<<1,64,0,stream>>>(out, 500.0f*303.0f); return; }
  const size_t NEED = 93215360;
  if (ws_size < NEED){ k_wssmall<<<1,64,0,stream>>>(out, 500.0f*304.0f); return; }

  // ---- workspace layout ----
  bf16* xw    = (bf16*) (ws);                    // 40,960,000 (first 80KB doubles as CSR 'counts')
  int*  cnt   = (int*)  (ws);                    // aliases xw: counts, live prep->scan
  bf16* act   = (bf16*) (ws + 40960000);         // -> 81,920,000 (first 80KB doubles as CSR 'cursor')
  int*  cursor= (int*)  (ws + 40960000);         // aliases act: live scan->scatter
  bf16* Xc    = (bf16*) (ws + 81920000);         // -> 87,040,000 (dead after gemm1)
  float* esC  = (float*)(ws + 81920000);         // aliases Xc: 80,000 B (layer-3 logits, H=1)
  float* edC  = (float*)(ws + 82000000);         // aliases Xc: 80,000 B
  bf16* Wt1   = (bf16*) (ws + 87040000);         // -> 87,302,144
  bf16* Wt2   = (bf16*) (ws + 87302144);         // -> 89,399,296
  bf16* Wt3   = (bf16*) (ws + 89399296);         // -> 90,447,872
  float* prm  = (float*)(ws + 90447872);         // -> 90,494,976
  int*  bsum  = (int*)  (ws + 90494976);         // 80 B (20 block sums; 256B gap before eic)
  int*  boff  = (int*)  (ws + 90495104);         // 80 B (20 block offsets)
  int*  eic   = (int*)  (ws + 90495232);         // -> 91,775,232 (dead after scatter)
  float* esB  = (float*)(ws + 90495232);         // aliases eic: 320,000 B (layer-2 logits)
  float* edB  = (float*)(ws + 90815232);         // aliases eic: 320,000 B
  float* esA  = (float*)(ws + 91775232);         // -> 92,095,232 (layer-1 logits)
  float* edA  = (float*)(ws + 92095232);         // -> 92,415,232
  int*  rp    = (int*)  (ws + 92415232);         // -> 92,495,360
  int*  col   = (int*)  (ws + 92495360);         // -> 93,215,360

  float *as1=prm+0, *ad1=prm+1024, *b1=prm+2048, *lg1=prm+3072, *lb1=prm+4096;
  float *as2=prm+5120, *ad2=prm+6144, *b2=prm+7168, *lg2=prm+8192, *lb2=prm+9216;
  float *as3=prm+10240, *ad3=prm+10752, *b3=prm+11264;

  const int TB = 256;
  int gbE = (EE + TB - 1)/TB;

  // ---- fused prep ----
  {
    PrepArgs A;
    A.xraw = d_in[0]; A.Xc = Xc;
    A.w1raw = d_in[2]; A.Wt1 = Wt1;
    A.w2raw = d_in[8]; A.Wt2 = Wt2;
    A.w3raw = d_in[14]; A.Wt3 = Wt3;
    A.eiraw = (const int*)d_in[1]; A.eic = eic;
    const int idx[13] = {3,4,5,6,7, 9,10,11,12,13, 15,16,17};
    const int off[13] = {0,1024,2048,3072,4096, 5120,6144,7168,8192,9216, 10240,10752,11264};
    const int nn [13] = {1024,1024,1024,1024,1024, 1024,1024,1024,1024,1024, 512,512,512};
    for (int i=0;i<13;i++){ A.p13.src[i]=d_in[idx[i]]; A.p13.off[i]=off[i]; A.p13.n[i]=nn[i]; }
    A.prm = prm; A.counts = cnt; A.esA = esA; A.edA = edA;
    k_prep<<<13006 + 313, TB, 0, stream>>>(A);
  }

  // ---- CSR (hierarchical scan: 20 blocks x 1024) ----
  const int NB = (NN + 1023)/1024;                // 20
  k_hist<<<gbE, TB, 0, stream>>>(eic, cnt);
  k_scanA<<<NB, 1024, 0, stream>>>(cnt, rp, bsum);
  k_scanB<<<1, 64, 0, stream>>>(bsum, boff, rp, NB);
  k_scanC<<<NB, 1024, 0, stream>>>(rp, boff, cursor, col);
  k_scatter<<<gbE, TB, 0, stream>>>(eic, cursor, col);

  const int RB = (NN + 63)/64;                    // 313 row-bands of 64
  const int R8 = ((RB + 7)/8)*8;                  // 320 (padded, guard in kernel)
  dim3 g12(1024/128, R8);
  dim3 g3 (512/128,  R8);

  // ---- layer 1 (K=128) ----
  k_gemm_mfma<<<g12, TB, 0, stream>>>(Xc, Wt1, xw, as1, ad1, esA, edA, 128, 1024, 256, 4);
  k_aggln<<<NN/2, 128, 0, stream>>>(rp, col, xw, esA, edA, b1, lg1, lb1, act, esB, edB, 4);

  // ---- layer 2 (K=1024) ----
  k_gemm_mfma<<<g12, TB, 0, stream>>>(act, Wt2, xw, as2, ad2, esB, edB, 1024, 1024, 256, 4);
  k_aggln<<<NN/2, 128, 0, stream>>>(rp, col, xw, esB, edB, b2, lg2, lb2, act, esC, edC, 1);

  // ---- layer 3 (K=1024, M=512) ----
  k_gemm_mfma<<<g3, TB, 0, stream>>>(act, Wt3, xw, as3, ad3, esC, edC, 1024, 512, 512, 1);
  k_agg3<<<NN/2, 128, 0, stream>>>(rp, col, xw, esC, edC, b3, out);
}

// Round 10
// 433.309 us; speedup vs baseline: 1.2855x; 1.0201x over previous
//
#include <hip/hip_runtime.h>
#include <hip/hip_bf16.h>

typedef __hip_bfloat16 bf16;
typedef __attribute__((ext_vector_type(8))) short short8;
typedef __attribute__((ext_vector_type(8))) unsigned short ushort8v;
typedef __attribute__((ext_vector_type(4))) float float4v;

#define NN 20000
#define EE 160000
#define ET (NN + EE)

__device__ __forceinline__ float bf2f(bf16 v){ return __bfloat162float(v); }
__device__ __forceinline__ float raw2f(unsigned short u){ return __uint_as_float(((unsigned)u) << 16); }
__device__ __forceinline__ unsigned short f2raw(float f){
  bf16 h = __float2bfloat16(f);
  return *(unsigned short*)&h;
}

// ---------------- inline dtype detection (per-wave ballot; all waves agree) ----------------
__device__ __forceinline__ int detect_f32(const void* raw, int nwords, int lane){
  unsigned v = ((const unsigned*)raw)[lane % nwords];
  int e8 = (v >> 7) & 0xFF;
  int looks = (e8 >= 100 && e8 <= 140) ? 1 : 0;
  unsigned long long mz = __ballot(v == 0u);
  unsigned long long ml = __ballot(looks);
  int nz = __popcll(mz);
  int nonz = 64 - nz;
  int nl = __popcll(ml);
  return (nonz > 0 && 2*nl >= nonz) ? 0 : 1;
}

__device__ __forceinline__ int detect_i64(const int* eiraw, int lane){
  int odd = eiraw[2*lane + 1];
  unsigned long long m2 = __ballot(odd != 0);
  return (m2 == 0ULL) ? 1 : 0;
}

// ---------------- fused preprocessing kernel ----------------
struct P13 { const void* src[13]; int off[13]; int n[13]; };
struct PrepArgs {
  const void* xraw; bf16* Xc;
  const void* w1raw; bf16* Wt1;
  const void* w2raw; bf16* Wt2;
  const void* w3raw; bf16* Wt3;
  const int* eiraw; int* eic;
  P13 p13; float* prm;
  int* counts;
  float* esA; float* edA;
};

__device__ __forceinline__ void do_transpose(float (*tile)[33], const void* raw,
    bf16* wt, int K, int M, int f, int bx, int by, int t){
  int kb = by*32, mb = bx*32;
  int tx = t & 31, ty = t >> 5;   // 32 x 8
  for (int r = 0; r < 4; r++){
    int k = kb + ty + r*8;
    int m = mb + tx;
    float v = f ? ((const float*)raw)[(size_t)k*M+m] : bf2f(((const bf16*)raw)[(size_t)k*M+m]);
    tile[ty + r*8][tx] = v;
  }
  __syncthreads();
  for (int r = 0; r < 4; r++){
    int m = mb + ty + r*8;
    int k = kb + tx;
    wt[(size_t)m*K + k] = __float2bfloat16(tile[tx][ty + r*8]);
  }
}

__global__ __launch_bounds__(256) void k_prep(PrepArgs A){
  __shared__ float tile[32][33];
  int b = blockIdx.x, t = threadIdx.x;
  int lane = t & 63;
  if (b < 10000){                                 // cvt X -> bf16
    int f = detect_f32(A.xraw, NN*128/2, lane);
    int i = b*256 + t;
    if (f) A.Xc[i] = __float2bfloat16(((const float*)A.xraw)[i]);
    else   A.Xc[i] = ((const bf16*)A.xraw)[i];
  } else if (b < 10128){                          // transpose W1 [128][1024] -> [1024][128]
    int f = detect_f32(A.w1raw, 128*1024/2, lane);
    int r = b - 10000;
    do_transpose(tile, A.w1raw, A.Wt1, 128, 1024, f, r & 31, r >> 5, t);
  } else if (b < 11152){                          // transpose W2 [1024][1024]
    int f = detect_f32(A.w2raw, 1024*1024/2, lane);
    int r = b - 10128;
    do_transpose(tile, A.w2raw, A.Wt2, 1024, 1024, f, r & 31, r >> 5, t);
  } else if (b < 11664){                          // transpose W3 [1024][512] -> [512][1024]
    int f = detect_f32(A.w3raw, 1024*512/2, lane);
    int r = b - 11152;
    do_transpose(tile, A.w3raw, A.Wt3, 1024, 512, f, r & 15, r >> 4, t);
  } else if (b < 12914){                          // cvte
    int f64 = detect_i64(A.eiraw, lane);
    int i = (b - 11664)*256 + t;
    if (i < 2*EE) A.eic[i] = f64 ? A.eiraw[2*i] : A.eiraw[i];
  } else if (b < 12927){                          // params -> fp32
    int pb = b - 12914;
    const void* s = A.p13.src[pb];
    int n = A.p13.n[pb];
    int f = detect_f32(s, n/2, lane);
    float* d = A.prm + A.p13.off[pb];
    for (int i = t; i < n; i += 256)
      d[i] = f ? ((const float*)s)[i] : bf2f(((const bf16*)s)[i]);
  } else if (b < 13006){                          // init_counts
    int i = (b - 12927)*256 + t;
    if (i < NN) A.counts[i] = 1;
  } else {                                        // zero esA/edA (NN*4 floats each)
    int i = (b - 13006)*256 + t;
    if (i < NN*4){ A.esA[i] = 0.f; A.edA[i] = 0.f; }
  }
}

// ---------------- CSR build ----------------
__global__ void k_hist(const int* __restrict__ ei, int* __restrict__ counts){
  int e = blockIdx.x*256 + threadIdx.x;
  if (e < EE){
    int d = ei[EE + e];
    if (d >= 0 && d < NN) atomicAdd(&counts[d], 1);
  }
}

// hierarchical scan (r7): 20 blocks local scan -> 1-wave scan of block sums -> apply + self-loop
__global__ __launch_bounds__(1024) void k_scanA(const int* __restrict__ counts, int* __restrict__ rp,
    int* __restrict__ bsum){
  __shared__ int wsum[16];
  int b = blockIdx.x, t = threadIdx.x, lane = t & 63, wv = t >> 6;
  int i = b*1024 + t;
  int v = (i < NN) ? counts[i] : 0;
  int x = v;
  #pragma unroll
  for (int o = 1; o < 64; o <<= 1){
    int y = __shfl_up(x, o, 64);
    if (lane >= o) x += y;
  }
  if (lane == 63) wsum[wv] = x;
  __syncthreads();
  if (wv == 0 && lane < 16){
    int w = wsum[lane];
    #pragma unroll
    for (int o = 1; o < 16; o <<= 1){
      int y = __shfl_up(w, o, 16);
      if (lane >= o) w += y;
    }
    wsum[lane] = w;
  }
  __syncthreads();
  int wpre = (wv > 0) ? wsum[wv-1] : 0;
  if (i < NN) rp[i] = wpre + x - v;      // block-local exclusive
  if (t == 1023) bsum[b] = wsum[15];     // block total
}

__global__ void k_scanB(const int* __restrict__ bsum, int* __restrict__ boff,
    int* __restrict__ rp, int nb){
  int t = threadIdx.x;                   // 64 threads, nb <= 64
  int v = (t < nb) ? bsum[t] : 0;
  int x = v;
  #pragma unroll
  for (int o = 1; o < 64; o <<= 1){
    int y = __shfl_up(x, o, 64);
    if (t >= o) x += y;
  }
  if (t < nb) boff[t] = x - v;           // exclusive block offsets
  if (t == 63) rp[NN] = x;               // grand total
}

__global__ __launch_bounds__(1024) void k_scanC(int* __restrict__ rp, const int* __restrict__ boff,
    int* __restrict__ cursor, int* __restrict__ col){
  int i = blockIdx.x*1024 + threadIdx.x;
  if (i < NN){
    int p = boff[blockIdx.x] + rp[i];
    rp[i] = p;
    col[p] = i;                          // self loop at segment head
    cursor[i] = p + 1;
  }
}

__global__ void k_scatter(const int* __restrict__ ei, int* __restrict__ cursor, int* __restrict__ col){
  int e = blockIdx.x*256 + threadIdx.x;
  if (e < EE){
    int s = ei[e], d = ei[EE + e];
    if (d >= 0 && d < NN){
      int pos = atomicAdd(&cursor[d], 1);
      col[pos] = s;
    }
  }
}

// ---------------- MFMA GEMM: 64x128 tile, BK=64, XOR-swizzled LDS, fused fp32 es/ed ----------------
// ROUND-0 STRUCTURE — FINAL. Five structural alternatives measured, all worse at these shapes
// (M=20000 tall-skinny, K=1024): r1 128^2 tile 94us (occ 23%); r2 dbuf+drain 89us; r3 dbuf+counted
// vmcnt 85.6us (occ 26%); r6 8-phase 256^2 port 158us (1 blk/CU, MfmaUtil 10%). This single-buffer
// 64x128 wins on block-TLP: ~3.3 blocks/CU, cross-block waves hide the per-K-step barrier drain.
// r9 lesson: layer-1 aggregate-then-project commutation FAILS verification (absmax 0.125 > 0.1025;
// the bf16 pipeline already sits at 0.0972 of a 0.1025 budget — no numerics headroom exists).
__global__ __launch_bounds__(256) void k_gemm_mfma(
    const bf16* __restrict__ X, const bf16* __restrict__ Wt, bf16* __restrict__ Y,
    const float* __restrict__ as_, const float* __restrict__ ad_,
    float* __restrict__ es, float* __restrict__ ed,
    int K, int M, int C, int H)
{
  __shared__ bf16 Xs[64*64];    // 8 KB
  __shared__ bf16 Bs[128*64];   // 16 KB
  int ncols = gridDim.x;
  int bid = blockIdx.y * ncols + blockIdx.x;
  int xcd  = bid & 7;
  int rest = bid >> 3;
  int colb = rest % ncols;
  int rowb = xcd + 8 * (rest / ncols);
  int r0 = rowb * 64;
  if (r0 >= NN) return;
  int c0 = colb * 128;

  int tid  = threadIdx.x;
  int wave = tid >> 6, lane = tid & 63;
  int quad = lane >> 4, l15 = lane & 15;
  int wr = (wave >> 1) * 32;     // 2 row-groups of 32
  int wc = (wave & 1) * 64;      // 2 col-groups of 64
  int sw = l15 & 7;

  float4v acc[2][4];
  #pragma unroll
  for (int i=0;i<2;i++)
    #pragma unroll
    for (int j=0;j<4;j++)
      acc[i][j] = (float4v){0.f,0.f,0.f,0.f};

  for (int k0 = 0; k0 < K; k0 += 64){
    #pragma unroll
    for (int i = 0; i < 2; i++){            // Xs: 512 chunks of 16B
      int ch = i*256 + tid;
      int row = ch >> 3, kl = ch & 7;
      int kg = kl ^ (row & 7);
      const bf16* gx = X + (size_t)(r0 + row)*K + k0 + kg*8;
      __builtin_amdgcn_global_load_lds(
        (const __attribute__((address_space(1))) unsigned int*)gx,
        (__attribute__((address_space(3))) unsigned int*)(Xs + ch*8), 16, 0, 0);
    }
    #pragma unroll
    for (int i = 0; i < 4; i++){            // Bs: 1024 chunks of 16B
      int ch = i*256 + tid;
      int row = ch >> 3, kl = ch & 7;
      int kg = kl ^ (row & 7);
      const bf16* gb = Wt + (size_t)(c0 + row)*K + k0 + kg*8;
      __builtin_amdgcn_global_load_lds(
        (const __attribute__((address_space(1))) unsigned int*)gb,
        (__attribute__((address_space(3))) unsigned int*)(Bs + ch*8), 16, 0, 0);
    }
    __syncthreads();

    #pragma unroll
    for (int kk = 0; kk < 2; kk++){         // two 32-wide K slices, in order (bit-identical accum)
      int kp = quad + kk*4;
      short8 af[2], bfr[4];
      #pragma unroll
      for (int i = 0; i < 2; i++){
        int r = wr + i*16 + l15;
        af[i] = *(const short8*)(Xs + ((size_t)r*8 + (kp ^ sw))*8);
      }
      #pragma unroll
      for (int j = 0; j < 4; j++){
        int r = wc + j*16 + l15;
        bfr[j] = *(const short8*)(Bs + ((size_t)r*8 + (kp ^ sw))*8);
      }
      #pragma unroll
      for (int i = 0; i < 2; i++)
        #pragma unroll
        for (int j = 0; j < 4; j++)
          acc[i][j] = __builtin_amdgcn_mfma_f32_16x16x32_bf16(af[i], bfr[j], acc[i][j], 0, 0, 0);
    }
    __syncthreads();
  }

  int h = c0 / C;
  float asv[4], adv[4];
  #pragma unroll
  for (int j = 0; j < 4; j++){
    int colj = c0 + wc + j*16 + l15;
    asv[j] = as_[colj]; adv[j] = ad_[colj];
  }
  #pragma unroll
  for (int i = 0; i < 2; i++){
    int rbase = r0 + wr + i*16 + quad*4;
    #pragma unroll
    for (int rg = 0; rg < 4; rg++){
      int row = rbase + rg;
      bool ok = (row < NN);
      float pe = 0.f, pd = 0.f;
      #pragma unroll
      for (int j = 0; j < 4; j++){
        float v = acc[i][j][rg];
        int colj = c0 + wc + j*16 + l15;
        if (ok) Y[(size_t)row*M + colj] = __float2bfloat16(v);
        pe += v * asv[j];
        pd += v * adv[j];
      }
      #pragma unroll
      for (int o = 1; o < 16; o <<= 1){
        pe += __shfl_xor(pe, o, 64);
        pd += __shfl_xor(pd, o, 64);
      }
      if (ok && l15 == 0){
        atomicAdd(&es[row*H + h], pe);
        atomicAdd(&ed[row*H + h], pd);
      }
    }
  }
}

// ---------------- wave-per-node softmax+aggregate+bias+LN+ELU (layers 1,2; H=4) ----------------
// r5 state: 128-thr blocks (2 waves) for fine-grain backfill of degree imbalance (+8us vs 256).
// r4 showed load-depth unrolling is neutral -> at the L3 random-2KB-gather floor (~5-6 TB/s eff).
__global__ __launch_bounds__(128) void k_aggln(const int* __restrict__ rp, const int* __restrict__ col,
    const bf16* __restrict__ xw, const float* __restrict__ es, const float* __restrict__ ed,
    const float* __restrict__ bias, const float* __restrict__ gam, const float* __restrict__ bet,
    bf16* __restrict__ act, float* __restrict__ esz, float* __restrict__ edz, int zn){
  int wv = threadIdx.x >> 6, lane = threadIdx.x & 63;
  int n = blockIdx.x*2 + wv;              // NN % 2 == 0
  int h = lane >> 4;
  int cb = lane * 16;
  int e0 = rp[n], e1 = rp[n+1], deg = e1 - e0;
  float4 ed4 = *(const float4*)&ed[n*4];
  const unsigned short* xwu = (const unsigned short*)xw;

  float acc[16];
  #pragma unroll
  for (int c=0;c<16;c++) acc[c]=0.f;

  if (deg <= 64){
    int src = 0;
    float l0=-1e30f, l1=-1e30f, l2=-1e30f, l3=-1e30f;
    if (lane < deg){
      src = col[e0 + lane];
      float4 e4 = *(const float4*)&es[src*4];
      float v;
      v = e4.x + ed4.x; l0 = v > 0.f ? v : 0.2f*v;
      v = e4.y + ed4.y; l1 = v > 0.f ? v : 0.2f*v;
      v = e4.z + ed4.z; l2 = v > 0.f ? v : 0.2f*v;
      v = e4.w + ed4.w; l3 = v > 0.f ? v : 0.2f*v;
    }
    float m0=l0, m1=l1, m2=l2, m3=l3;
    #pragma unroll
    for (int o=1;o<64;o<<=1){
      m0 = fmaxf(m0, __shfl_xor(m0,o,64));
      m1 = fmaxf(m1, __shfl_xor(m1,o,64));
      m2 = fmaxf(m2, __shfl_xor(m2,o,64));
      m3 = fmaxf(m3, __shfl_xor(m3,o,64));
    }
    float p0 = (lane<deg) ? __expf(l0-m0) : 0.f;
    float p1 = (lane<deg) ? __expf(l1-m1) : 0.f;
    float p2 = (lane<deg) ? __expf(l2-m2) : 0.f;
    float p3 = (lane<deg) ? __expf(l3-m3) : 0.f;
    float d0=p0, d1=p1, d2=p2, d3=p3;
    #pragma unroll
    for (int o=1;o<64;o<<=1){
      d0 += __shfl_xor(d0,o,64);
      d1 += __shfl_xor(d1,o,64);
      d2 += __shfl_xor(d2,o,64);
      d3 += __shfl_xor(d3,o,64);
    }
    float al0 = p0 * (1.f/(d0+1e-16f));
    float al1 = p1 * (1.f/(d1+1e-16f));
    float al2 = p2 * (1.f/(d2+1e-16f));
    float al3 = p3 * (1.f/(d3+1e-16f));

    int j = 0;
    for (; j + 4 <= deg; j += 4){
      int sA = __shfl(src, j, 64);
      int sB = __shfl(src, j+1, 64);
      int sC = __shfl(src, j+2, 64);
      int sD = __shfl(src, j+3, 64);
      float a0A = __shfl(al0, j, 64),   a1A = __shfl(al1, j, 64);
      float a2A = __shfl(al2, j, 64),   a3A = __shfl(al3, j, 64);
      float a0B = __shfl(al0, j+1, 64), a1B = __shfl(al1, j+1, 64);
      float a2B = __shfl(al2, j+1, 64), a3B = __shfl(al3, j+1, 64);
      float a0C = __shfl(al0, j+2, 64), a1C = __shfl(al1, j+2, 64);
      float a2C = __shfl(al2, j+2, 64), a3C = __shfl(al3, j+2, 64);
      float a0D = __shfl(al0, j+3, 64), a1D = __shfl(al1, j+3, 64);
      float a2D = __shfl(al2, j+3, 64), a3D = __shfl(al3, j+3, 64);
      float aA = (h==0) ? a0A : ((h==1) ? a1A : ((h==2) ? a2A : a3A));
      float aB = (h==0) ? a0B : ((h==1) ? a1B : ((h==2) ? a2B : a3B));
      float aC = (h==0) ? a0C : ((h==1) ? a1C : ((h==2) ? a2C : a3C));
      float aD = (h==0) ? a0D : ((h==1) ? a1D : ((h==2) ? a2D : a3D));
      const unsigned short* rA = xwu + (size_t)sA*1024 + cb;
      const unsigned short* rB = xwu + (size_t)sB*1024 + cb;
      const unsigned short* rC = xwu + (size_t)sC*1024 + cb;
      const unsigned short* rD = xwu + (size_t)sD*1024 + cb;
      ushort8v uA0 = *(const ushort8v*)(rA);
      ushort8v uA1 = *(const ushort8v*)(rA+8);
      ushort8v uB0 = *(const ushort8v*)(rB);
      ushort8v uB1 = *(const ushort8v*)(rB+8);
      ushort8v uC0 = *(const ushort8v*)(rC);
      ushort8v uC1 = *(const ushort8v*)(rC+8);
      ushort8v uD0 = *(const ushort8v*)(rD);
      ushort8v uD1 = *(const ushort8v*)(rD+8);
      #pragma unroll
      for (int c=0;c<8;c++){ acc[c]   += aA*raw2f(uA0[c]); acc[8+c] += aA*raw2f(uA1[c]); }
      #pragma unroll
      for (int c=0;c<8;c++){ acc[c]   += aB*raw2f(uB0[c]); acc[8+c] += aB*raw2f(uB1[c]); }
      #pragma unroll
      for (int c=0;c<8;c++){ acc[c]   += aC*raw2f(uC0[c]); acc[8+c] += aC*raw2f(uC1[c]); }
      #pragma unroll
      for (int c=0;c<8;c++){ acc[c]   += aD*raw2f(uD0[c]); acc[8+c] += aD*raw2f(uD1[c]); }
    }
    for (; j < deg; j++){
      int s = __shfl(src, j, 64);
      float a0j = __shfl(al0, j, 64);
      float a1j = __shfl(al1, j, 64);
      float a2j = __shfl(al2, j, 64);
      float a3j = __shfl(al3, j, 64);
      float aj = (h==0) ? a0j : ((h==1) ? a1j : ((h==2) ? a2j : a3j));
      const unsigned short* row = xwu + (size_t)s*1024 + cb;
      ushort8v u0 = *(const ushort8v*)(row);
      ushort8v u1 = *(const ushort8v*)(row+8);
      #pragma unroll
      for (int c=0;c<8;c++){ acc[c] += aj*raw2f(u0[c]); acc[8+c] += aj*raw2f(u1[c]); }
    }
  } else {
    float edh = (h==0) ? ed4.x : ((h==1) ? ed4.y : ((h==2) ? ed4.z : ed4.w));
    float m = -1e30f;
    for (int e=e0;e<e1;e++){
      float v = es[col[e]*4 + h] + edh;
      v = v > 0.f ? v : 0.2f*v;
      m = fmaxf(m, v);
    }
    float den = 0.f;
    for (int e=e0;e<e1;e++){
      float v = es[col[e]*4 + h] + edh;
      v = v > 0.f ? v : 0.2f*v;
      den += __expf(v - m);
    }
    float rd = 1.f/(den + 1e-16f);
    for (int e=e0;e<e1;e++){
      int s = col[e];
      float v = es[s*4 + h] + edh;
      v = v > 0.f ? v : 0.2f*v;
      float aj = __expf(v - m) * rd;
      const unsigned short* row = xwu + (size_t)s*1024 + cb;
      ushort8v u0 = *(const ushort8v*)(row);
      ushort8v u1 = *(const ushort8v*)(row+8);
      #pragma unroll
      for (int c=0;c<8;c++){ acc[c] += aj*raw2f(u0[c]); acc[8+c] += aj*raw2f(u1[c]); }
    }
  }

  #pragma unroll
  for (int c=0;c<16;c++) acc[c] += bias[cb+c];
  float s1 = 0.f, s2 = 0.f;
  #pragma unroll
  for (int c=0;c<16;c++){ s1 += acc[c]; s2 += acc[c]*acc[c]; }
  #pragma unroll
  for (int o=1;o<64;o<<=1){
    s1 += __shfl_xor(s1,o,64);
    s2 += __shfl_xor(s2,o,64);
  }
  float mu  = s1 * (1.f/1024.f);
  float var = s2 * (1.f/1024.f) - mu*mu;
  float rstd = rsqrtf(fmaxf(var, 0.f) + 1e-5f);

  ushort4 o4[4];
  #pragma unroll
  for (int q=0;q<4;q++){
    float v0 = (acc[q*4+0]-mu)*rstd*gam[cb+q*4+0] + bet[cb+q*4+0];
    float v1 = (acc[q*4+1]-mu)*rstd*gam[cb+q*4+1] + bet[cb+q*4+1];
    float v2 = (acc[q*4+2]-mu)*rstd*gam[cb+q*4+2] + bet[cb+q*4+2];
    float v3 = (acc[q*4+3]-mu)*rstd*gam[cb+q*4+3] + bet[cb+q*4+3];
    v0 = v0 > 0.f ? v0 : (__expf(v0)-1.f);
    v1 = v1 > 0.f ? v1 : (__expf(v1)-1.f);
    v2 = v2 > 0.f ? v2 : (__expf(v2)-1.f);
    v3 = v3 > 0.f ? v3 : (__expf(v3)-1.f);
    o4[q].x = f2raw(v0); o4[q].y = f2raw(v1); o4[q].z = f2raw(v2); o4[q].w = f2raw(v3);
  }
  unsigned short* dst = (unsigned short*)act + (size_t)n*1024 + cb;
  *(ushort4*)(dst)    = o4[0];
  *(ushort4*)(dst+4)  = o4[1];
  *(ushort4*)(dst+8)  = o4[2];
  *(ushort4*)(dst+12) = o4[3];

  // zero next layer's logit slots for this node (exclusive ownership; read next dispatch)
  if (lane < zn){ esz[n*zn + lane] = 0.f; edz[n*zn + lane] = 0.f; }
}

// ---------------- wave-per-node layer-3: softmax + aggregate + bias -> fp32 out (H=1) ----------------
__global__ __launch_bounds__(128) void k_agg3(const int* __restrict__ rp, const int* __restrict__ col,
    const bf16* __restrict__ xw, const float* __restrict__ es, const float* __restrict__ ed,
    const float* __restrict__ bias, float* __restrict__ out){
  int wv = threadIdx.x >> 6, lane = threadIdx.x & 63;
  int n = blockIdx.x*2 + wv;
  int cb = lane * 8;
  int e0 = rp[n], e1 = rp[n+1], deg = e1 - e0;
  float edv = ed[n];
  const unsigned short* xwu = (const unsigned short*)xw;

  float acc[8];
  #pragma unroll
  for (int c=0;c<8;c++) acc[c]=0.f;

  if (deg <= 64){
    int src = 0;
    float l = -1e30f;
    if (lane < deg){
      src = col[e0 + lane];
      float v = es[src] + edv;
      l = v > 0.f ? v : 0.2f*v;
    }
    float m = l;
    #pragma unroll
    for (int o=1;o<64;o<<=1) m = fmaxf(m, __shfl_xor(m,o,64));
    float p = (lane<deg) ? __expf(l-m) : 0.f;
    float d = p;
    #pragma unroll
    for (int o=1;o<64;o<<=1) d += __shfl_xor(d,o,64);
    float al = p * (1.f/(d+1e-16f));

    int j = 0;
    for (; j + 4 <= deg; j += 4){
      int sA = __shfl(src, j, 64);
      int sB = __shfl(src, j+1, 64);
      int sC = __shfl(src, j+2, 64);
      int sD = __shfl(src, j+3, 64);
      float aA = __shfl(al, j, 64);
      float aB = __shfl(al, j+1, 64);
      float aC = __shfl(al, j+2, 64);
      float aD = __shfl(al, j+3, 64);
      const unsigned short* rA = xwu + (size_t)sA*512 + cb;
      const unsigned short* rB = xwu + (size_t)sB*512 + cb;
      const unsigned short* rC = xwu + (size_t)sC*512 + cb;
      const unsigned short* rD = xwu + (size_t)sD*512 + cb;
      ushort8v uA = *(const ushort8v*)(rA);
      ushort8v uB = *(const ushort8v*)(rB);
      ushort8v uC = *(const ushort8v*)(rC);
      ushort8v uD = *(const ushort8v*)(rD);
      #pragma unroll
      for (int c=0;c<8;c++) acc[c] += aA*raw2f(uA[c]);
      #pragma unroll
      for (int c=0;c<8;c++) acc[c] += aB*raw2f(uB[c]);
      #pragma unroll
      for (int c=0;c<8;c++) acc[c] += aC*raw2f(uC[c]);
      #pragma unroll
      for (int c=0;c<8;c++) acc[c] += aD*raw2f(uD[c]);
    }
    for (; j < deg; j++){
      int s = __shfl(src, j, 64);
      float aj = __shfl(al, j, 64);
      const unsigned short* row = xwu + (size_t)s*512 + cb;
      ushort8v u = *(const ushort8v*)(row);
      #pragma unroll
      for (int c=0;c<8;c++) acc[c] += aj*raw2f(u[c]);
    }
  } else {
    float m = -1e30f;
    for (int e=e0;e<e1;e++){
      float v = es[col[e]] + edv;
      v = v > 0.f ? v : 0.2f*v;
      m = fmaxf(m, v);
    }
    float den = 0.f;
    for (int e=e0;e<e1;e++){
      float v = es[col[e]] + edv;
      v = v > 0.f ? v : 0.2f*v;
      den += __expf(v - m);
    }
    float rd = 1.f/(den + 1e-16f);
    for (int e=e0;e<e1;e++){
      int s = col[e];
      float v = es[s] + edv;
      v = v > 0.f ? v : 0.2f*v;
      float aj = __expf(v - m) * rd;
      const unsigned short* row = xwu + (size_t)s*512 + cb;
      ushort8v u = *(const ushort8v*)(row);
      #pragma unroll
      for (int c=0;c<8;c++) acc[c] += aj*raw2f(u[c]);
    }
  }
  float* dst = out + (size_t)n*512 + cb;
  #pragma unroll
  for (int c=0;c<8;c++) dst[c] = acc[c] + bias[cb+c];
}

__global__ void k_wssmall(float* __restrict__ out, float code){
  if (threadIdx.x == 0) out[0] = code;
}

// ---------------- launch ----------------
extern "C" void kernel_launch(void* const* d_in, const int* in_sizes, int n_in,
                              void* d_out, int out_size, void* d_ws, size_t ws_size,
                              hipStream_t stream){
  float* out = (float*)d_out;
  char* ws = (char*)d_ws;

  static const int EXP_SZ[18] = {2560000, 320000, 131072, 1024,1024,1024,1024,1024,
                                 1048576, 1024,1024,1024,1024,1024,
                                 524288, 512,512,512};
  if (n_in != 18){ k_wssmall<<<1,64,0,stream>>>(out, 500.0f*301.0f); return; }
  for (int i = 0; i < 18; i++)
    if (in_sizes[i] != EXP_SZ[i]){ k_wssmall<<<1,64,0,stream>>>(out, 500.0f*302.0f); return; }
  if (out_size != NN*512){ k_wssmall<<<1,64,0,stream>>>(out, 500.0f*303.0f); return; }
  const size_t NEED = 93215360;
  if (ws_size < NEED){ k_wssmall<<<1,64,0,stream>>>(out, 500.0f*304.0f); return; }

  // ---- workspace layout ----
  bf16* xw    = (bf16*) (ws);                    // 40,960,000 (first 80KB doubles as CSR 'counts')
  int*  cnt   = (int*)  (ws);                    // aliases xw: counts, live prep->scanA
  bf16* act   = (bf16*) (ws + 40960000);         // -> 81,920,000 (first 80KB doubles as CSR 'cursor')
  int*  cursor= (int*)  (ws + 40960000);         // aliases act: live scanC->scatter
  bf16* Xc    = (bf16*) (ws + 81920000);         // -> 87,040,000 (dead after gemm1)
  float* esC  = (float*)(ws + 81920000);         // aliases Xc: 80,000 B (layer-3 logits, H=1)
  float* edC  = (float*)(ws + 82000000);         // aliases Xc: 80,000 B
  bf16* Wt1   = (bf16*) (ws + 87040000);         // -> 87,302,144
  bf16* Wt2   = (bf16*) (ws + 87302144);         // -> 89,399,296
  bf16* Wt3   = (bf16*) (ws + 89399296);         // -> 90,447,872
  float* prm  = (float*)(ws + 90447872);         // -> 90,494,976
  int*  bsum  = (int*)  (ws + 90494976);         // 80 B (20 block sums; 256B gap before eic)
  int*  boff  = (int*)  (ws + 90495104);         // 80 B (20 block offsets)
  int*  eic   = (int*)  (ws + 90495232);         // -> 91,775,232 (dead after scatter)
  float* esB  = (float*)(ws + 90495232);         // aliases eic: 320,000 B (layer-2 logits)
  float* edB  = (float*)(ws + 90815232);         // aliases eic: 320,000 B
  float* esA  = (float*)(ws + 91775232);         // -> 92,095,232 (layer-1 logits)
  float* edA  = (float*)(ws + 92095232);         // -> 92,415,232
  int*  rp    = (int*)  (ws + 92415232);         // -> 92,495,360
  int*  col   = (int*)  (ws + 92495360);         // -> 93,215,360

  float *as1=prm+0, *ad1=prm+1024, *b1=prm+2048, *lg1=prm+3072, *lb1=prm+4096;
  float *as2=prm+5120, *ad2=prm+6144, *b2=prm+7168, *lg2=prm+8192, *lb2=prm+9216;
  float *as3=prm+10240, *ad3=prm+10752, *b3=prm+11264;

  const int TB = 256;
  int gbE = (EE + TB - 1)/TB;

  // ---- fused prep ----
  {
    PrepArgs A;
    A.xraw = d_in[0]; A.Xc = Xc;
    A.w1raw = d_in[2]; A.Wt1 = Wt1;
    A.w2raw = d_in[8]; A.Wt2 = Wt2;
    A.w3raw = d_in[14]; A.Wt3 = Wt3;
    A.eiraw = (const int*)d_in[1]; A.eic = eic;
    const int idx[13] = {3,4,5,6,7, 9,10,11,12,13, 15,16,17};
    const int off[13] = {0,1024,2048,3072,4096, 5120,6144,7168,8192,9216, 10240,10752,11264};
    const int nn [13] = {1024,1024,1024,1024,1024, 1024,1024,1024,1024,1024, 512,512,512};
    for (int i=0;i<13;i++){ A.p13.src[i]=d_in[idx[i]]; A.p13.off[i]=off[i]; A.p13.n[i]=nn[i]; }
    A.prm = prm; A.counts = cnt; A.esA = esA; A.edA = edA;
    k_prep<<<13006 + 313, TB, 0, stream>>>(A);
  }

  // ---- CSR (hierarchical scan: 20 blocks x 1024) ----
  const int NB = (NN + 1023)/1024;                // 20
  k_hist<<<gbE, TB, 0, stream>>>(eic, cnt);
  k_scanA<<<NB, 1024, 0, stream>>>(cnt, rp, bsum);
  k_scanB<<<1, 64, 0, stream>>>(bsum, boff, rp, NB);
  k_scanC<<<NB, 1024, 0, stream>>>(rp, boff, cursor, col);
  k_scatter<<<gbE, TB, 0, stream>>>(eic, cursor, col);

  const int RB = (NN + 63)/64;                    // 313 row-bands of 64
  const int R8 = ((RB + 7)/8)*8;                  // 320 (padded, guard in kernel)
  dim3 g12(1024/128, R8);
  dim3 g3 (512/128,  R8);

  // ---- layer 1 (K=128) ----
  k_gemm_mfma<<<g12, TB, 0, stream>>>(Xc, Wt1, xw, as1, ad1, esA, edA, 128, 1024, 256, 4);
  k_aggln<<<NN/2, 128, 0, stream>>>(rp, col, xw, esA, edA, b1, lg1, lb1, act, esB, edB, 4);

  // ---- layer 2 (K=1024) ----
  k_gemm_mfma<<<g12, TB, 0, stream>>>(act, Wt2, xw, as2, ad2, esB, edB, 1024, 1024, 256, 4);
  k_aggln<<<NN/2, 128, 0, stream>>>(rp, col, xw, esB, edB, b2, lg2, lb2, act, esC, edC, 1);

  // ---- layer 3 (K=1024, M=512) ----
  k_gemm_mfma<<<g3, TB, 0, stream>>>(act, Wt3, xw, as3, ad3, esC, edC, 1024, 512, 512, 1);
  k_agg3<<<NN/2, 128, 0, stream>>>(rp, col, xw, esC, edC, b3, out);
}